// Round 7
// baseline (626.857 us; speedup 1.0000x reference)
//
#include <hip/hip_runtime.h>
#include <cstdint>
#include <cstddef>

#define N_NODES 10000
#define M_PAD   10112            // 79 * 128
#define N_EDGES 160000
#define ETOT    (N_EDGES + N_NODES)   // with self-loops
#define F_INDIM 300
#define K1PAD   320              // F_INDIM padded to mult of 32
#define HEADS   4
#define DH      256
#define C1      (HEADS * DH)     // 1024
#define NCLS    6
#define BN_EPS  1e-5f

typedef _Float16 half8 __attribute__((ext_vector_type(8)));
typedef _Float16 half4 __attribute__((ext_vector_type(4)));
typedef float f32x4 __attribute__((ext_vector_type(4)));

__device__ __forceinline__ void gld_lds16(const void* g, void* s) {
  __builtin_amdgcn_global_load_lds(
      (const __attribute__((address_space(1))) void*)g,
      (__attribute__((address_space(3))) void*)s, 16, 0, 0);
}

// ---------------------------------------------------------------------------
// fp16 MFMA GEMM: C[M,Nn] = A[M,K]fp16 @ B[Nn,K]fp16^T  (NT)
// 128x128 tile, BK=32, 256 threads = 4 waves (2x2), 4x4 16x16x32 frags/wave.
// OUT16=1 -> fp16 output, else fp32.
// ---------------------------------------------------------------------------
template <int OUT16>
__global__ __launch_bounds__(256) void k_mfma_gemm(
    const _Float16* __restrict__ A, const _Float16* __restrict__ B,
    float* __restrict__ Cf, _Float16* __restrict__ Ch,
    int M, int Nn, int K) {
  __shared__ __align__(16) _Float16 sA[128 * 32];
  __shared__ __align__(16) _Float16 sB[128 * 32];
  const int tid = threadIdx.x;
  const int lane = tid & 63, w = tid >> 6;
  const int wm = w >> 1, wn = w & 1;
  const int row0 = blockIdx.y * 128, col0 = blockIdx.x * 128;

  const int r_loc = lane >> 2;       // 0..15
  const int j8 = (lane & 3) * 8;     // half offset within BK=32
  const _Float16* gA = A + (size_t)(row0 + w * 32 + r_loc) * K + j8;
  const _Float16* gB = B + (size_t)(col0 + w * 32 + r_loc) * K + j8;
  _Float16* sAw = sA + (w * 32) * 32;
  _Float16* sBw = sB + (w * 32) * 32;

  const int fr = lane & 15, kb = lane >> 4;
  const _Float16* pA = sA + ((size_t)(wm * 64 + fr) * 32 + kb * 8);
  const _Float16* pB = sB + ((size_t)(wn * 64 + fr) * 32 + kb * 8);

  f32x4 acc[4][4] = {};
  const int KT = K / 32;

  {
    gld_lds16(gA, sAw);
    gld_lds16(gA + (size_t)16 * K, sAw + 16 * 32);
    gld_lds16(gB, sBw);
    gld_lds16(gB + (size_t)16 * K, sBw + 16 * 32);
  }
  for (int kt = 0; kt < KT; ++kt) {
    __syncthreads();
    half8 af[4], bf[4];
#pragma unroll
    for (int i = 0; i < 4; ++i) af[i] = *(const half8*)(pA + i * 16 * 32);
#pragma unroll
    for (int j = 0; j < 4; ++j) bf[j] = *(const half8*)(pB + j * 16 * 32);
    __syncthreads();
    if (kt + 1 < KT) {
      const _Float16* ga = gA + (size_t)(kt + 1) * 32;
      const _Float16* gb = gB + (size_t)(kt + 1) * 32;
      gld_lds16(ga, sAw);
      gld_lds16(ga + (size_t)16 * K, sAw + 16 * 32);
      gld_lds16(gb, sBw);
      gld_lds16(gb + (size_t)16 * K, sBw + 16 * 32);
    }
#pragma unroll
    for (int i = 0; i < 4; ++i)
#pragma unroll
      for (int j = 0; j < 4; ++j)
        acc[i][j] =
            __builtin_amdgcn_mfma_f32_16x16x32_f16(af[i], bf[j], acc[i][j], 0, 0, 0);
  }

  // C/D layout: col = lane&15, row = (lane>>4)*4 + reg
  const int orow = row0 + wm * 64 + kb * 4;
  const int ocol = col0 + wn * 64 + fr;
#pragma unroll
  for (int i = 0; i < 4; ++i) {
#pragma unroll
    for (int r = 0; r < 4; ++r) {
      const int rr = orow + i * 16 + r;
      if (rr >= M) continue;
#pragma unroll
      for (int j = 0; j < 4; ++j) {
        if (OUT16) Ch[(size_t)rr * Nn + ocol + j * 16] = (_Float16)acc[i][j][r];
        else       Cf[(size_t)rr * Nn + ocol + j * 16] = acc[i][j][r];
      }
    }
  }
}

// ---------------------------------------------------------------------------
// fp32 -> fp16 conversion with K padding (zeros for k >= K)
// ---------------------------------------------------------------------------
__global__ __launch_bounds__(256) void k_cvt(const float* __restrict__ in,
                                             _Float16* __restrict__ out,
                                             int M, int K, int Kpad) {
  const int idx = blockIdx.x * 256 + threadIdx.x;
  const int kp2 = Kpad >> 1;
  if (idx >= M * kp2) return;
  const int r = idx / kp2, c2 = (idx % kp2) * 2;
  const float vx = (c2 < K) ? in[(size_t)r * K + c2] : 0.f;
  const float vy = (c2 + 1 < K) ? in[(size_t)r * K + c2 + 1] : 0.f;
  out[(size_t)r * Kpad + c2] = (_Float16)vx;
  out[(size_t)r * Kpad + c2 + 1] = (_Float16)vy;
}

// ---------------------------------------------------------------------------
// Fused MLP head: out = fc2( relu( fc1(h) ) ), 8 nodes per block.
// ---------------------------------------------------------------------------
#define MLP_NPB 8
__global__ __launch_bounds__(256) void k_mlp(
    const float* __restrict__ h, const float* __restrict__ W1,
    const float* __restrict__ b1, const float* __restrict__ W2,
    const float* __restrict__ b2, float* __restrict__ out) {
  __shared__ float sh[MLP_NPB * 256];   // 8 input rows (8 KB)
  __shared__ float sy[MLP_NPB][132];    // relu(fc1) padded (4.2 KB)
  const int tid = threadIdx.x;
  const int n0 = blockIdx.x * MLP_NPB;
  {
    const float4* src = (const float4*)(h + (size_t)n0 * 256);
    float4* dst = (float4*)sh;
    dst[tid] = src[tid];
    dst[tid + 256] = src[tid + 256];
  }
  __syncthreads();
  const int j = tid & 127;   // fc1 output index
  const int g = tid >> 7;    // node group: nodes g*4 .. g*4+3
  const float bj = b1[j];
  float a0 = bj, a1 = bj, a2 = bj, a3 = bj;
  const float4* wrow = (const float4*)(W1 + (size_t)j * 256);
  const float4* h0 = (const float4*)(sh + (g * 4 + 0) * 256);
  const float4* h1 = (const float4*)(sh + (g * 4 + 1) * 256);
  const float4* h2 = (const float4*)(sh + (g * 4 + 2) * 256);
  const float4* h3 = (const float4*)(sh + (g * 4 + 3) * 256);
#pragma unroll 8
  for (int k = 0; k < 64; ++k) {
    const float4 w = wrow[k];
    const float4 v0 = h0[k], v1 = h1[k], v2 = h2[k], v3 = h3[k];
    a0 += w.x * v0.x + w.y * v0.y + w.z * v0.z + w.w * v0.w;
    a1 += w.x * v1.x + w.y * v1.y + w.z * v1.z + w.w * v1.w;
    a2 += w.x * v2.x + w.y * v2.y + w.z * v2.z + w.w * v2.w;
    a3 += w.x * v3.x + w.y * v3.y + w.z * v3.z + w.w * v3.w;
  }
  sy[g * 4 + 0][j] = a0 > 0.f ? a0 : 0.f;
  sy[g * 4 + 1][j] = a1 > 0.f ? a1 : 0.f;
  sy[g * 4 + 2][j] = a2 > 0.f ? a2 : 0.f;
  sy[g * 4 + 3][j] = a3 > 0.f ? a3 : 0.f;
  __syncthreads();
  if (tid < MLP_NPB * NCLS) {  // 48 threads
    const int n = tid / NCLS, c = tid % NCLS;
    float s = b2[c];
    const float* w2 = W2 + c * 128;
#pragma unroll 8
    for (int k = 0; k < 128; ++k) s += sy[n][k] * w2[k];
    out[(size_t)(n0 + n) * NCLS + c] = s;
  }
}

// ---------------------------------------------------------------------------
// alpha_s[n,h] = <h[n,h,:], a_src[h,:]> from fp16 h. Block = HH*64.
// ---------------------------------------------------------------------------
template <int HH>
__global__ __launch_bounds__(HH * 64) void k_alpha(
    const _Float16* __restrict__ h, const float* __restrict__ a_src,
    const float* __restrict__ a_dst, float* __restrict__ as_,
    float* __restrict__ ad_) {
  const int n = blockIdx.x;
  const int tid = threadIdx.x;
  const int head = tid >> 6;
  const int lane = tid & 63;
  const half4 hv = *(const half4*)(h + (size_t)n * HH * DH + head * DH + lane * 4);
  const float4 sv = *(reinterpret_cast<const float4*>(a_src + head * DH) + lane);
  const float4 dv = *(reinterpret_cast<const float4*>(a_dst + head * DH) + lane);
  const float h0 = (float)hv[0], h1 = (float)hv[1], h2 = (float)hv[2],
              h3 = (float)hv[3];
  float s1 = h0 * sv.x + h1 * sv.y + h2 * sv.z + h3 * sv.w;
  float s2 = h0 * dv.x + h1 * dv.y + h2 * dv.z + h3 * dv.w;
#pragma unroll
  for (int off = 32; off > 0; off >>= 1) {
    s1 += __shfl_down(s1, off);
    s2 += __shfl_down(s2, off);
  }
  if (lane == 0) {
    as_[n * HH + head] = s1;
    ad_[n * HH + head] = s2;
  }
}

// ---------------------------------------------------------------------------
// Per edge: all heads. w = exp(leaky_relu(as[src]+ad[dst])); write into CSR
// slot order (einv) so aggregation reads weights contiguously.
// ---------------------------------------------------------------------------
template <int HH>
__global__ __launch_bounds__(256) void k_edge(
    const int* __restrict__ ei, const int* __restrict__ einv,
    float* __restrict__ ewc, float* __restrict__ den,
    const float* __restrict__ as_, const float* __restrict__ ad_) {
  const int e = blockIdx.x * 256 + threadIdx.x;
  if (e >= ETOT) return;
  int s, t;
  if (e < N_EDGES) { s = ei[e]; t = ei[N_EDGES + e]; }
  else             { s = t = e - N_EDGES; }
  const int pos = einv[e];
#pragma unroll
  for (int hh = 0; hh < HH; ++hh) {
    float x = as_[s * HH + hh] + ad_[t * HH + hh];
    x = x > 0.f ? x : 0.2f * x;
    const float w = expf(x);
    ewc[(size_t)pos * HH + hh] = w;
    atomicAdd(&den[t * HH + hh], w);
  }
}

// ---------------------------------------------------------------------------
// CSR build
// ---------------------------------------------------------------------------
__global__ __launch_bounds__(256) void k_count(const int* __restrict__ ei,
                                               int* __restrict__ cnt) {
  const int e = blockIdx.x * 256 + threadIdx.x;
  if (e >= ETOT) return;
  const int t = (e < N_EDGES) ? ei[N_EDGES + e] : (e - N_EDGES);
  atomicAdd(&cnt[t], 1);
}

__global__ __launch_bounds__(256) void k_scan(const int* __restrict__ cnt,
                                              int* __restrict__ rowptr) {
  __shared__ int part[256];
  const int tid = threadIdx.x;
  const int chunk = (N_NODES + 255) / 256;  // 40
  const int b = tid * chunk;
  int sum = 0;
  for (int i = 0; i < chunk; i++) {
    const int idx = b + i;
    if (idx < N_NODES) sum += cnt[idx];
  }
  part[tid] = sum;
  __syncthreads();
  for (int off = 1; off < 256; off <<= 1) {
    int t2 = (tid >= off) ? part[tid - off] : 0;
    __syncthreads();
    part[tid] += t2;
    __syncthreads();
  }
  int run = part[tid] - sum;
  for (int i = 0; i < chunk; i++) {
    const int idx = b + i;
    if (idx < N_NODES) {
      rowptr[idx] = run;
      run += cnt[idx];
    }
  }
  if (tid == 255) rowptr[N_NODES] = part[255];
}

__global__ __launch_bounds__(256) void k_fill(
    const int* __restrict__ ei, const int* __restrict__ rowptr,
    int* __restrict__ fill, int* __restrict__ csr_src,
    int* __restrict__ einv) {
  const int e = blockIdx.x * 256 + threadIdx.x;
  if (e >= ETOT) return;
  int s, t;
  if (e < N_EDGES) { s = ei[e]; t = ei[N_EDGES + e]; }
  else             { s = t = e - N_EDGES; }
  const int pos = rowptr[t] + atomicAdd(&fill[t], 1);
  csr_src[pos] = s;
  einv[e] = pos;
}

// ---------------------------------------------------------------------------
// Aggregation from fp16 h. HH=4: 128 threads/node, 16B (half8) per-lane
// gathers -- round-6 postmortem: gather is REQUEST-rate limited (fp32/16B
// version hit 7 TB/s L2-side; fp16/8B only 4.4), so halve requests by
// doubling per-lane payload. HH=1: 64 threads, half4 (unchanged geometry).
// ---------------------------------------------------------------------------
template <int HH, bool DO_BN>
__global__ __launch_bounds__((HH == 4) ? 128 : 64) void k_agg(
    const _Float16* __restrict__ h, const int* __restrict__ rowptr,
    const int* __restrict__ csr_src, const float* __restrict__ ewc,
    const float* __restrict__ den, const float* __restrict__ bias,
    const float* __restrict__ gg, const float* __restrict__ be,
    const float* __restrict__ mm, const float* __restrict__ vv,
    float* __restrict__ outf, _Float16* __restrict__ outh) {
  constexpr int NT = (HH == 4) ? 128 : 64;     // threads per block
  constexpr int CPT = (HH * 256) / NT;         // cols per thread: 8 or 4
  const int C = HH * 256;
  const int n = blockIdx.x;
  const int tid = threadIdx.x;
  const int c0 = tid * CPT;
  const int head = c0 >> 8;
  __shared__ int s_src[64];
  __shared__ float s_al[64 * HH];
  const float idn = 1.f / (den[n * HH + head] + 1e-16f);
  float acc[CPT] = {};
  const int beg = rowptr[n], end = rowptr[n + 1];
  for (int base = beg; base < end; base += 64) {
    const int cnt = min(64, end - base);
    __syncthreads();
    for (int k = tid; k < cnt; k += NT) s_src[k] = csr_src[base + k];
    for (int k = tid; k < cnt * HH; k += NT) s_al[k] = ewc[(size_t)base * HH + k];
    __syncthreads();
    int j = 0;
    const int nfull = cnt & ~3;
    for (; j < nfull; j += 4) {
      float w[4];
      half8 v8[4];
      half4 v4[4];
#pragma unroll
      for (int u = 0; u < 4; ++u) {
        w[u] = s_al[(j + u) * HH + head];
        const _Float16* src = h + (size_t)s_src[j + u] * C + c0;
        if (CPT == 8) v8[u] = *(const half8*)src;
        else          v4[u] = *(const half4*)src;
      }
#pragma unroll
      for (int u = 0; u < 4; ++u) {
#pragma unroll
        for (int i = 0; i < CPT; ++i)
          acc[i] += (float)((CPT == 8) ? v8[u][i] : v4[u][i]) * w[u];
      }
    }
    for (; j < cnt; ++j) {
      const float w0 = s_al[j * HH + head];
      const _Float16* src = h + (size_t)s_src[j] * C + c0;
      if (CPT == 8) {
        const half8 v = *(const half8*)src;
#pragma unroll
        for (int i = 0; i < CPT; ++i) acc[i] += (float)v[i] * w0;
      } else {
        const half4 v = *(const half4*)src;
#pragma unroll
        for (int i = 0; i < CPT; ++i) acc[i] += (float)v[i] * w0;
      }
    }
  }
#pragma unroll
  for (int i = 0; i < CPT; i++) {
    const int c = c0 + i;
    float val = acc[i] * idn + bias[c];
    if (DO_BN) val = (val - mm[c]) * rsqrtf(vv[c] + BN_EPS) * gg[c] + be[c];
    val = val > 0.f ? val : expm1f(val);  // ELU
    if (outh) outh[(size_t)n * C + c] = (_Float16)val;
    else      outf[(size_t)n * C + c] = val;
  }
}

// ---------------------------------------------------------------------------
extern "C" void kernel_launch(void* const* d_in, const int* in_sizes, int n_in,
                              void* d_out, int out_size, void* d_ws,
                              size_t ws_size, hipStream_t stream) {
  const float* x    = (const float*)d_in[0];
  const int*   ei   = (const int*)d_in[1];
  const float* W1   = (const float*)d_in[2];
  const float* a1s  = (const float*)d_in[3];
  const float* a1d  = (const float*)d_in[4];
  const float* b1   = (const float*)d_in[5];
  const float* W2   = (const float*)d_in[6];
  const float* a2s  = (const float*)d_in[7];
  const float* a2d  = (const float*)d_in[8];
  const float* b2   = (const float*)d_in[9];
  const float* W3   = (const float*)d_in[10];
  const float* a3s  = (const float*)d_in[11];
  const float* a3d  = (const float*)d_in[12];
  const float* b3   = (const float*)d_in[13];
  const float* g1   = (const float*)d_in[14];
  const float* be1  = (const float*)d_in[15];
  const float* m1   = (const float*)d_in[16];
  const float* v1   = (const float*)d_in[17];
  const float* g2   = (const float*)d_in[18];
  const float* be2  = (const float*)d_in[19];
  const float* m2   = (const float*)d_in[20];
  const float* v2   = (const float*)d_in[21];
  const float* fc1W = (const float*)d_in[22];
  const float* fc1b = (const float*)d_in[23];
  const float* fc2W = (const float*)d_in[24];
  const float* fc2b = (const float*)d_in[25];
  float* out = (float*)d_out;

  char* p = (char*)d_ws;
  auto alloc = [&](size_t bytes) -> void* {
    void* r = (void*)p;
    p += (bytes + 255) & ~(size_t)255;
    return r;
  };
  _Float16* hA     = (_Float16*)alloc((size_t)M_PAD * C1 * 2);  // GEMM input (holds xh first)
  _Float16* hG     = (_Float16*)alloc((size_t)M_PAD * C1 * 2);  // GEMM output
  _Float16* wh     = (_Float16*)alloc((size_t)C1 * C1 * 2);
  float*    buf1   = (float*)alloc((size_t)N_NODES * DH * 4);   // agg3 out -> MLP in
  float*    as_    = (float*)alloc((size_t)N_NODES * HEADS * 4);
  float*    ad_    = (float*)alloc((size_t)N_NODES * HEADS * 4);
  float*    den    = (float*)alloc((size_t)N_NODES * HEADS * 4);
  float*    ewc    = (float*)alloc((size_t)ETOT * HEADS * 4);
  int*      rowptr = (int*)alloc((size_t)(N_NODES + 1) * 4);
  int*      cnt    = (int*)alloc((size_t)N_NODES * 4);
  int*      csrS   = (int*)alloc((size_t)ETOT * 4);
  int*      einv   = (int*)alloc((size_t)ETOT * 4);

  const int eb = (ETOT + 255) / 256;
  _Float16* xh = hA;  // alias: [M_PAD][K1PAD]

  // ---- CSR build (graph identical for all three layers) ----
  hipMemsetAsync(cnt, 0, (size_t)N_NODES * 4, stream);
  k_count<<<eb, 256, 0, stream>>>(ei, cnt);
  k_scan<<<1, 256, 0, stream>>>(cnt, rowptr);
  hipMemsetAsync(cnt, 0, (size_t)N_NODES * 4, stream);
  k_fill<<<eb, 256, 0, stream>>>(ei, rowptr, cnt, csrS, einv);

  // ---- Layer 1: GATConv(300 -> 4x256) + BN1 + ELU ----
  k_cvt<<<(N_NODES * (K1PAD / 2) + 255) / 256, 256, 0, stream>>>(
      x, xh, N_NODES, F_INDIM, K1PAD);
  k_cvt<<<(C1 * (K1PAD / 2) + 255) / 256, 256, 0, stream>>>(
      W1, wh, C1, F_INDIM, K1PAD);
  k_mfma_gemm<1><<<dim3(C1 / 128, M_PAD / 128), 256, 0, stream>>>(
      xh, wh, nullptr, hG, N_NODES, C1, K1PAD);
  k_alpha<4><<<N_NODES, 256, 0, stream>>>(hG, a1s, a1d, as_, ad_);
  hipMemsetAsync(den, 0, (size_t)N_NODES * HEADS * 4, stream);
  k_edge<4><<<eb, 256, 0, stream>>>(ei, einv, ewc, den, as_, ad_);
  k_agg<4, true><<<N_NODES, 128, 0, stream>>>(hG, rowptr, csrS, ewc, den,
                                              b1, g1, be1, m1, v1, nullptr, hA);

  // ---- Layer 2: GATConv(1024 -> 4x256) + BN2 + ELU ----
  k_cvt<<<(C1 * (C1 / 2) + 255) / 256, 256, 0, stream>>>(W2, wh, C1, C1, C1);
  k_mfma_gemm<1><<<dim3(C1 / 128, M_PAD / 128), 256, 0, stream>>>(
      hA, wh, nullptr, hG, N_NODES, C1, C1);
  k_alpha<4><<<N_NODES, 256, 0, stream>>>(hG, a2s, a2d, as_, ad_);
  hipMemsetAsync(den, 0, (size_t)N_NODES * HEADS * 4, stream);
  k_edge<4><<<eb, 256, 0, stream>>>(ei, einv, ewc, den, as_, ad_);
  k_agg<4, true><<<N_NODES, 128, 0, stream>>>(hG, rowptr, csrS, ewc, den,
                                              b2, g2, be2, m2, v2, nullptr, hA);

  // ---- Layer 3: GATConv(1024 -> 256, heads=1) + ELU ----
  k_cvt<<<(DH * (C1 / 2) + 255) / 256, 256, 0, stream>>>(W3, wh, DH, C1, C1);
  k_mfma_gemm<1><<<dim3(DH / 128, M_PAD / 128), 256, 0, stream>>>(
      hA, wh, nullptr, hG, N_NODES, DH, C1);
  k_alpha<1><<<N_NODES, 64, 0, stream>>>(hG, a3s, a3d, as_, ad_);
  hipMemsetAsync(den, 0, (size_t)N_NODES * 4, stream);
  k_edge<1><<<eb, 256, 0, stream>>>(ei, einv, ewc, den, as_, ad_);
  k_agg<1, false><<<N_NODES, 64, 0, stream>>>(hG, rowptr, csrS, ewc, den,
                                              b3, nullptr, nullptr, nullptr,
                                              nullptr, buf1, nullptr);

  // ---- Fused MLP head ----
  k_mlp<<<N_NODES / MLP_NPB, 256, 0, stream>>>(buf1, fc1W, fc1b, fc2W, fc2b,
                                               out);
}

// Round 8
// 612.271 us; speedup vs baseline: 1.0238x; 1.0238x over previous
//
#include <hip/hip_runtime.h>
#include <cstdint>
#include <cstddef>

#define N_NODES 10000
#define M_PAD   10112            // 79 * 128
#define N_EDGES 160000
#define ETOT    (N_EDGES + N_NODES)   // with self-loops
#define F_INDIM 300
#define K1PAD   320              // F_INDIM padded to mult of 32
#define HEADS   4
#define DH      256
#define C1      (HEADS * DH)     // 1024
#define NCLS    6
#define BN_EPS  1e-5f

typedef _Float16 half8 __attribute__((ext_vector_type(8)));
typedef _Float16 half4 __attribute__((ext_vector_type(4)));
typedef float f32x4 __attribute__((ext_vector_type(4)));

__device__ __forceinline__ void gld_lds16(const void* g, void* s) {
  __builtin_amdgcn_global_load_lds(
      (const __attribute__((address_space(1))) void*)g,
      (__attribute__((address_space(3))) void*)s, 16, 0, 0);
}

// ---------------------------------------------------------------------------
// fp16 MFMA GEMM: C[M,Nn] = A[M,K]fp16 @ B[Nn,K]fp16^T  (NT)
// 128x128 tile, BK=32, 256 threads = 4 waves (2x2), 4x4 16x16x32 frags/wave.
// OUT16=1 -> fp16 output, else fp32.
// ---------------------------------------------------------------------------
template <int OUT16>
__global__ __launch_bounds__(256) void k_mfma_gemm(
    const _Float16* __restrict__ A, const _Float16* __restrict__ B,
    float* __restrict__ Cf, _Float16* __restrict__ Ch,
    int M, int Nn, int K) {
  __shared__ __align__(16) _Float16 sA[128 * 32];
  __shared__ __align__(16) _Float16 sB[128 * 32];
  const int tid = threadIdx.x;
  const int lane = tid & 63, w = tid >> 6;
  const int wm = w >> 1, wn = w & 1;
  const int row0 = blockIdx.y * 128, col0 = blockIdx.x * 128;

  const int r_loc = lane >> 2;       // 0..15
  const int j8 = (lane & 3) * 8;     // half offset within BK=32
  const _Float16* gA = A + (size_t)(row0 + w * 32 + r_loc) * K + j8;
  const _Float16* gB = B + (size_t)(col0 + w * 32 + r_loc) * K + j8;
  _Float16* sAw = sA + (w * 32) * 32;
  _Float16* sBw = sB + (w * 32) * 32;

  const int fr = lane & 15, kb = lane >> 4;
  const _Float16* pA = sA + ((size_t)(wm * 64 + fr) * 32 + kb * 8);
  const _Float16* pB = sB + ((size_t)(wn * 64 + fr) * 32 + kb * 8);

  f32x4 acc[4][4] = {};
  const int KT = K / 32;

  {
    gld_lds16(gA, sAw);
    gld_lds16(gA + (size_t)16 * K, sAw + 16 * 32);
    gld_lds16(gB, sBw);
    gld_lds16(gB + (size_t)16 * K, sBw + 16 * 32);
  }
  for (int kt = 0; kt < KT; ++kt) {
    __syncthreads();
    half8 af[4], bf[4];
#pragma unroll
    for (int i = 0; i < 4; ++i) af[i] = *(const half8*)(pA + i * 16 * 32);
#pragma unroll
    for (int j = 0; j < 4; ++j) bf[j] = *(const half8*)(pB + j * 16 * 32);
    __syncthreads();
    if (kt + 1 < KT) {
      const _Float16* ga = gA + (size_t)(kt + 1) * 32;
      const _Float16* gb = gB + (size_t)(kt + 1) * 32;
      gld_lds16(ga, sAw);
      gld_lds16(ga + (size_t)16 * K, sAw + 16 * 32);
      gld_lds16(gb, sBw);
      gld_lds16(gb + (size_t)16 * K, sBw + 16 * 32);
    }
#pragma unroll
    for (int i = 0; i < 4; ++i)
#pragma unroll
      for (int j = 0; j < 4; ++j)
        acc[i][j] =
            __builtin_amdgcn_mfma_f32_16x16x32_f16(af[i], bf[j], acc[i][j], 0, 0, 0);
  }

  // C/D layout: col = lane&15, row = (lane>>4)*4 + reg
  const int orow = row0 + wm * 64 + kb * 4;
  const int ocol = col0 + wn * 64 + fr;
#pragma unroll
  for (int i = 0; i < 4; ++i) {
#pragma unroll
    for (int r = 0; r < 4; ++r) {
      const int rr = orow + i * 16 + r;
      if (rr >= M) continue;
#pragma unroll
      for (int j = 0; j < 4; ++j) {
        if (OUT16) Ch[(size_t)rr * Nn + ocol + j * 16] = (_Float16)acc[i][j][r];
        else       Cf[(size_t)rr * Nn + ocol + j * 16] = acc[i][j][r];
      }
    }
  }
}

// ---------------------------------------------------------------------------
// fp32 -> fp16 conversion with K padding (zeros for k >= K)
// ---------------------------------------------------------------------------
__global__ __launch_bounds__(256) void k_cvt(const float* __restrict__ in,
                                             _Float16* __restrict__ out,
                                             int M, int K, int Kpad) {
  const int idx = blockIdx.x * 256 + threadIdx.x;
  const int kp2 = Kpad >> 1;
  if (idx >= M * kp2) return;
  const int r = idx / kp2, c2 = (idx % kp2) * 2;
  const float vx = (c2 < K) ? in[(size_t)r * K + c2] : 0.f;
  const float vy = (c2 + 1 < K) ? in[(size_t)r * K + c2 + 1] : 0.f;
  out[(size_t)r * Kpad + c2] = (_Float16)vx;
  out[(size_t)r * Kpad + c2 + 1] = (_Float16)vy;
}

// ---------------------------------------------------------------------------
// Fused MLP head: out = fc2( relu( fc1(h) ) ), 8 nodes per block.
// ---------------------------------------------------------------------------
#define MLP_NPB 8
__global__ __launch_bounds__(256) void k_mlp(
    const float* __restrict__ h, const float* __restrict__ W1,
    const float* __restrict__ b1, const float* __restrict__ W2,
    const float* __restrict__ b2, float* __restrict__ out) {
  __shared__ float sh[MLP_NPB * 256];   // 8 input rows (8 KB)
  __shared__ float sy[MLP_NPB][132];    // relu(fc1) padded (4.2 KB)
  const int tid = threadIdx.x;
  const int n0 = blockIdx.x * MLP_NPB;
  {
    const float4* src = (const float4*)(h + (size_t)n0 * 256);
    float4* dst = (float4*)sh;
    dst[tid] = src[tid];
    dst[tid + 256] = src[tid + 256];
  }
  __syncthreads();
  const int j = tid & 127;   // fc1 output index
  const int g = tid >> 7;    // node group: nodes g*4 .. g*4+3
  const float bj = b1[j];
  float a0 = bj, a1 = bj, a2 = bj, a3 = bj;
  const float4* wrow = (const float4*)(W1 + (size_t)j * 256);
  const float4* h0 = (const float4*)(sh + (g * 4 + 0) * 256);
  const float4* h1 = (const float4*)(sh + (g * 4 + 1) * 256);
  const float4* h2 = (const float4*)(sh + (g * 4 + 2) * 256);
  const float4* h3 = (const float4*)(sh + (g * 4 + 3) * 256);
#pragma unroll 8
  for (int k = 0; k < 64; ++k) {
    const float4 w = wrow[k];
    const float4 v0 = h0[k], v1 = h1[k], v2 = h2[k], v3 = h3[k];
    a0 += w.x * v0.x + w.y * v0.y + w.z * v0.z + w.w * v0.w;
    a1 += w.x * v1.x + w.y * v1.y + w.z * v1.z + w.w * v1.w;
    a2 += w.x * v2.x + w.y * v2.y + w.z * v2.z + w.w * v2.w;
    a3 += w.x * v3.x + w.y * v3.y + w.z * v3.z + w.w * v3.w;
  }
  sy[g * 4 + 0][j] = a0 > 0.f ? a0 : 0.f;
  sy[g * 4 + 1][j] = a1 > 0.f ? a1 : 0.f;
  sy[g * 4 + 2][j] = a2 > 0.f ? a2 : 0.f;
  sy[g * 4 + 3][j] = a3 > 0.f ? a3 : 0.f;
  __syncthreads();
  if (tid < MLP_NPB * NCLS) {  // 48 threads
    const int n = tid / NCLS, c = tid % NCLS;
    float s = b2[c];
    const float* w2 = W2 + c * 128;
#pragma unroll 8
    for (int k = 0; k < 128; ++k) s += sy[n][k] * w2[k];
    out[(size_t)(n0 + n) * NCLS + c] = s;
  }
}

// ---------------------------------------------------------------------------
// alpha_s[n,h] = <h[n,h,:], a_src[h,:]> from fp16 h. Block = HH*64.
// ---------------------------------------------------------------------------
template <int HH>
__global__ __launch_bounds__(HH * 64) void k_alpha(
    const _Float16* __restrict__ h, const float* __restrict__ a_src,
    const float* __restrict__ a_dst, float* __restrict__ as_,
    float* __restrict__ ad_) {
  const int n = blockIdx.x;
  const int tid = threadIdx.x;
  const int head = tid >> 6;
  const int lane = tid & 63;
  const half4 hv = *(const half4*)(h + (size_t)n * HH * DH + head * DH + lane * 4);
  const float4 sv = *(reinterpret_cast<const float4*>(a_src + head * DH) + lane);
  const float4 dv = *(reinterpret_cast<const float4*>(a_dst + head * DH) + lane);
  const float h0 = (float)hv[0], h1 = (float)hv[1], h2 = (float)hv[2],
              h3 = (float)hv[3];
  float s1 = h0 * sv.x + h1 * sv.y + h2 * sv.z + h3 * sv.w;
  float s2 = h0 * dv.x + h1 * dv.y + h2 * dv.z + h3 * dv.w;
#pragma unroll
  for (int off = 32; off > 0; off >>= 1) {
    s1 += __shfl_down(s1, off);
    s2 += __shfl_down(s2, off);
  }
  if (lane == 0) {
    as_[n * HH + head] = s1;
    ad_[n * HH + head] = s2;
  }
}

// ---------------------------------------------------------------------------
// Per edge: all heads. w = exp(leaky_relu(as[src]+ad[dst])); write into CSR
// slot order (einv) so aggregation reads weights contiguously.
// ---------------------------------------------------------------------------
template <int HH>
__global__ __launch_bounds__(256) void k_edge(
    const int* __restrict__ ei, const int* __restrict__ einv,
    float* __restrict__ ewc, float* __restrict__ den,
    const float* __restrict__ as_, const float* __restrict__ ad_) {
  const int e = blockIdx.x * 256 + threadIdx.x;
  if (e >= ETOT) return;
  int s, t;
  if (e < N_EDGES) { s = ei[e]; t = ei[N_EDGES + e]; }
  else             { s = t = e - N_EDGES; }
  const int pos = einv[e];
#pragma unroll
  for (int hh = 0; hh < HH; ++hh) {
    float x = as_[s * HH + hh] + ad_[t * HH + hh];
    x = x > 0.f ? x : 0.2f * x;
    const float w = expf(x);
    ewc[(size_t)pos * HH + hh] = w;
    atomicAdd(&den[t * HH + hh], w);
  }
}

// ---------------------------------------------------------------------------
// CSR build
// ---------------------------------------------------------------------------
__global__ __launch_bounds__(256) void k_count(const int* __restrict__ ei,
                                               int* __restrict__ cnt) {
  const int e = blockIdx.x * 256 + threadIdx.x;
  if (e >= ETOT) return;
  const int t = (e < N_EDGES) ? ei[N_EDGES + e] : (e - N_EDGES);
  atomicAdd(&cnt[t], 1);
}

__global__ __launch_bounds__(256) void k_scan(const int* __restrict__ cnt,
                                              int* __restrict__ rowptr) {
  __shared__ int part[256];
  const int tid = threadIdx.x;
  const int chunk = (N_NODES + 255) / 256;  // 40
  const int b = tid * chunk;
  int sum = 0;
  for (int i = 0; i < chunk; i++) {
    const int idx = b + i;
    if (idx < N_NODES) sum += cnt[idx];
  }
  part[tid] = sum;
  __syncthreads();
  for (int off = 1; off < 256; off <<= 1) {
    int t2 = (tid >= off) ? part[tid - off] : 0;
    __syncthreads();
    part[tid] += t2;
    __syncthreads();
  }
  int run = part[tid] - sum;
  for (int i = 0; i < chunk; i++) {
    const int idx = b + i;
    if (idx < N_NODES) {
      rowptr[idx] = run;
      run += cnt[idx];
    }
  }
  if (tid == 255) rowptr[N_NODES] = part[255];
}

__global__ __launch_bounds__(256) void k_fill(
    const int* __restrict__ ei, const int* __restrict__ rowptr,
    int* __restrict__ fill, int* __restrict__ csr_src,
    int* __restrict__ einv) {
  const int e = blockIdx.x * 256 + threadIdx.x;
  if (e >= ETOT) return;
  int s, t;
  if (e < N_EDGES) { s = ei[e]; t = ei[N_EDGES + e]; }
  else             { s = t = e - N_EDGES; }
  const int pos = rowptr[t] + atomicAdd(&fill[t], 1);
  csr_src[pos] = s;
  einv[e] = pos;
}

// ---------------------------------------------------------------------------
// HH=4 aggregation. Round-8 geometry: 256 thr/node (40K waves TLP, as R6) AND
// 16B/lane half8 gathers (as R3's 7 TB/s config). Wave pair (parity) splits
// edges; wave halves split columns: wave w -> cols [(w>>1)*512, +512),
// edges j = (w&1), (w&1)+2, ... Cross-wave LDS reduce + epilogue at end.
// ---------------------------------------------------------------------------
template <bool DO_BN>
__global__ __launch_bounds__(256) void k_agg4(
    const _Float16* __restrict__ h, const int* __restrict__ rowptr,
    const int* __restrict__ csr_src, const float* __restrict__ ewc,
    const float* __restrict__ den, const float* __restrict__ bias,
    const float* __restrict__ gg, const float* __restrict__ be,
    const float* __restrict__ mm, const float* __restrict__ vv,
    _Float16* __restrict__ outh) {
  const int n = blockIdx.x;
  const int tid = threadIdx.x;
  const int lane = tid & 63, w = tid >> 6;
  const int half = w >> 1;              // column half: 0 or 1
  const int par = w & 1;                // edge parity
  const int c0 = half * 512 + lane * 8; // 8 cols per lane (one head)
  const int head = c0 >> 8;
  __shared__ int s_src[64];
  __shared__ float s_al[64 * 4];
  __shared__ float s_red[2][512];
  const float idn = 1.f / (den[n * 4 + head] + 1e-16f);
  float acc[8] = {};
  const int beg = rowptr[n], end = rowptr[n + 1];
  for (int base = beg; base < end; base += 64) {
    const int cnt = min(64, end - base);
    __syncthreads();
    if (tid < cnt) s_src[tid] = csr_src[base + tid];
    if (tid < cnt * 4) s_al[tid] = ewc[(size_t)base * 4 + tid];
    __syncthreads();
    int j = par;
    for (; j + 6 < cnt; j += 8) {   // 4 edges (stride 2) in flight
      float ww[4];
      half8 v[4];
#pragma unroll
      for (int u = 0; u < 4; ++u) {
        const int jj = j + 2 * u;
        ww[u] = s_al[jj * 4 + head];
        v[u] = *(const half8*)(h + (size_t)s_src[jj] * C1 + c0);
      }
#pragma unroll
      for (int u = 0; u < 4; ++u)
#pragma unroll
        for (int i = 0; i < 8; ++i) acc[i] += (float)v[u][i] * ww[u];
    }
    for (; j < cnt; j += 2) {
      const float w0 = s_al[j * 4 + head];
      const half8 v = *(const half8*)(h + (size_t)s_src[j] * C1 + c0);
#pragma unroll
      for (int i = 0; i < 8; ++i) acc[i] += (float)v[i] * w0;
    }
  }
  __syncthreads();
  if (par == 1) {
#pragma unroll
    for (int i = 0; i < 8; ++i) s_red[half][lane * 8 + i] = acc[i];
  }
  __syncthreads();
  if (par == 0) {
    half8 ov;
#pragma unroll
    for (int i = 0; i < 8; ++i) {
      float val = (acc[i] + s_red[half][lane * 8 + i]) * idn;
      const int c = c0 + i;
      val += bias[c];
      if (DO_BN) val = (val - mm[c]) * rsqrtf(vv[c] + BN_EPS) * gg[c] + be[c];
      val = val > 0.f ? val : expm1f(val);  // ELU
      ov[i] = (_Float16)val;
    }
    *(half8*)(outh + (size_t)n * C1 + c0) = ov;
  }
}

// ---------------------------------------------------------------------------
// HH=1 aggregation (layer 3): R6 geometry, 64 thr, half4, fp32 out, ELU.
// ---------------------------------------------------------------------------
__global__ __launch_bounds__(64) void k_agg1(
    const _Float16* __restrict__ h, const int* __restrict__ rowptr,
    const int* __restrict__ csr_src, const float* __restrict__ ewc,
    const float* __restrict__ den, const float* __restrict__ bias,
    float* __restrict__ outf) {
  const int n = blockIdx.x;
  const int tid = threadIdx.x;
  const int c0 = tid * 4;
  __shared__ int s_src[64];
  __shared__ float s_al[64];
  const float idn = 1.f / (den[n] + 1e-16f);
  float acc[4] = {};
  const int beg = rowptr[n], end = rowptr[n + 1];
  for (int base = beg; base < end; base += 64) {
    const int cnt = min(64, end - base);
    __syncthreads();
    if (tid < cnt) {
      s_src[tid] = csr_src[base + tid];
      s_al[tid] = ewc[base + tid];
    }
    __syncthreads();
    int j = 0;
    const int nfull = cnt & ~7;
    for (; j < nfull; j += 8) {
      float w[8];
      half4 v[8];
#pragma unroll
      for (int u = 0; u < 8; ++u) {
        w[u] = s_al[j + u];
        v[u] = *(const half4*)(h + (size_t)s_src[j + u] * DH + c0);
      }
#pragma unroll
      for (int u = 0; u < 8; ++u)
#pragma unroll
        for (int i = 0; i < 4; ++i) acc[i] += (float)v[u][i] * w[u];
    }
    for (; j < cnt; ++j) {
      const float w0 = s_al[j];
      const half4 v = *(const half4*)(h + (size_t)s_src[j] * DH + c0);
#pragma unroll
      for (int i = 0; i < 4; ++i) acc[i] += (float)v[i] * w0;
    }
  }
#pragma unroll
  for (int i = 0; i < 4; i++) {
    const int c = c0 + i;
    float val = acc[i] * idn + bias[c];
    val = val > 0.f ? val : expm1f(val);  // ELU
    outf[(size_t)n * DH + c] = val;
  }
}

// ---------------------------------------------------------------------------
extern "C" void kernel_launch(void* const* d_in, const int* in_sizes, int n_in,
                              void* d_out, int out_size, void* d_ws,
                              size_t ws_size, hipStream_t stream) {
  const float* x    = (const float*)d_in[0];
  const int*   ei   = (const int*)d_in[1];
  const float* W1   = (const float*)d_in[2];
  const float* a1s  = (const float*)d_in[3];
  const float* a1d  = (const float*)d_in[4];
  const float* b1   = (const float*)d_in[5];
  const float* W2   = (const float*)d_in[6];
  const float* a2s  = (const float*)d_in[7];
  const float* a2d  = (const float*)d_in[8];
  const float* b2   = (const float*)d_in[9];
  const float* W3   = (const float*)d_in[10];
  const float* a3s  = (const float*)d_in[11];
  const float* a3d  = (const float*)d_in[12];
  const float* b3   = (const float*)d_in[13];
  const float* g1   = (const float*)d_in[14];
  const float* be1  = (const float*)d_in[15];
  const float* m1   = (const float*)d_in[16];
  const float* v1   = (const float*)d_in[17];
  const float* g2   = (const float*)d_in[18];
  const float* be2  = (const float*)d_in[19];
  const float* m2   = (const float*)d_in[20];
  const float* v2   = (const float*)d_in[21];
  const float* fc1W = (const float*)d_in[22];
  const float* fc1b = (const float*)d_in[23];
  const float* fc2W = (const float*)d_in[24];
  const float* fc2b = (const float*)d_in[25];
  float* out = (float*)d_out;

  char* p = (char*)d_ws;
  auto alloc = [&](size_t bytes) -> void* {
    void* r = (void*)p;
    p += (bytes + 255) & ~(size_t)255;
    return r;
  };
  _Float16* hA     = (_Float16*)alloc((size_t)M_PAD * C1 * 2);  // GEMM input (holds xh first)
  _Float16* hG     = (_Float16*)alloc((size_t)M_PAD * C1 * 2);  // GEMM output
  _Float16* wh     = (_Float16*)alloc((size_t)C1 * C1 * 2);
  float*    buf1   = (float*)alloc((size_t)N_NODES * DH * 4);   // agg3 out -> MLP in
  float*    as_    = (float*)alloc((size_t)N_NODES * HEADS * 4);
  float*    ad_    = (float*)alloc((size_t)N_NODES * HEADS * 4);
  float*    den    = (float*)alloc((size_t)N_NODES * HEADS * 4);
  float*    ewc    = (float*)alloc((size_t)ETOT * HEADS * 4);
  int*      rowptr = (int*)alloc((size_t)(N_NODES + 1) * 4);
  int*      cnt    = (int*)alloc((size_t)N_NODES * 4);
  int*      csrS   = (int*)alloc((size_t)ETOT * 4);
  int*      einv   = (int*)alloc((size_t)ETOT * 4);

  const int eb = (ETOT + 255) / 256;
  _Float16* xh = hA;  // alias: [M_PAD][K1PAD]

  // ---- CSR build (graph identical for all three layers) ----
  hipMemsetAsync(cnt, 0, (size_t)N_NODES * 4, stream);
  k_count<<<eb, 256, 0, stream>>>(ei, cnt);
  k_scan<<<1, 256, 0, stream>>>(cnt, rowptr);
  hipMemsetAsync(cnt, 0, (size_t)N_NODES * 4, stream);
  k_fill<<<eb, 256, 0, stream>>>(ei, rowptr, cnt, csrS, einv);

  // ---- Layer 1: GATConv(300 -> 4x256) + BN1 + ELU ----
  k_cvt<<<(N_NODES * (K1PAD / 2) + 255) / 256, 256, 0, stream>>>(
      x, xh, N_NODES, F_INDIM, K1PAD);
  k_cvt<<<(C1 * (K1PAD / 2) + 255) / 256, 256, 0, stream>>>(
      W1, wh, C1, F_INDIM, K1PAD);
  k_mfma_gemm<1><<<dim3(C1 / 128, M_PAD / 128), 256, 0, stream>>>(
      xh, wh, nullptr, hG, N_NODES, C1, K1PAD);
  k_alpha<4><<<N_NODES, 256, 0, stream>>>(hG, a1s, a1d, as_, ad_);
  hipMemsetAsync(den, 0, (size_t)N_NODES * HEADS * 4, stream);
  k_edge<4><<<eb, 256, 0, stream>>>(ei, einv, ewc, den, as_, ad_);
  k_agg4<true><<<N_NODES, 256, 0, stream>>>(hG, rowptr, csrS, ewc, den,
                                            b1, g1, be1, m1, v1, hA);

  // ---- Layer 2: GATConv(1024 -> 4x256) + BN2 + ELU ----
  k_cvt<<<(C1 * (C1 / 2) + 255) / 256, 256, 0, stream>>>(W2, wh, C1, C1, C1);
  k_mfma_gemm<1><<<dim3(C1 / 128, M_PAD / 128), 256, 0, stream>>>(
      hA, wh, nullptr, hG, N_NODES, C1, C1);
  k_alpha<4><<<N_NODES, 256, 0, stream>>>(hG, a2s, a2d, as_, ad_);
  hipMemsetAsync(den, 0, (size_t)N_NODES * HEADS * 4, stream);
  k_edge<4><<<eb, 256, 0, stream>>>(ei, einv, ewc, den, as_, ad_);
  k_agg4<true><<<N_NODES, 256, 0, stream>>>(hG, rowptr, csrS, ewc, den,
                                            b2, g2, be2, m2, v2, hA);

  // ---- Layer 3: GATConv(1024 -> 256, heads=1) + ELU ----
  k_cvt<<<(DH * (C1 / 2) + 255) / 256, 256, 0, stream>>>(W3, wh, DH, C1, C1);
  k_mfma_gemm<1><<<dim3(DH / 128, M_PAD / 128), 256, 0, stream>>>(
      hA, wh, nullptr, hG, N_NODES, DH, C1);
  k_alpha<1><<<N_NODES, 64, 0, stream>>>(hG, a3s, a3d, as_, ad_);
  hipMemsetAsync(den, 0, (size_t)N_NODES * 4, stream);
  k_edge<1><<<eb, 256, 0, stream>>>(ei, einv, ewc, den, as_, ad_);
  k_agg1<<<N_NODES, 64, 0, stream>>>(hG, rowptr, csrS, ewc, den, b3, buf1);

  // ---- Fused MLP head ----
  k_mlp<<<N_NODES / MLP_NPB, 256, 0, stream>>>(buf1, fc1W, fc1b, fc2W, fc2b,
                                               out);
}

// Round 11
// 484.792 us; speedup vs baseline: 1.2930x; 1.2630x over previous
//
#include <hip/hip_runtime.h>
#include <cstdint>
#include <cstddef>

#define N_NODES 10000
#define M_PAD   10112            // 79 * 128
#define N_EDGES 160000
#define ETOT    (N_EDGES + N_NODES)   // with self-loops
#define F_INDIM 300
#define K1PAD   320              // F_INDIM padded to mult of 32
#define HEADS   4
#define DH      256
#define C1      (HEADS * DH)     // 1024
#define NCLS    6
#define BN_EPS  1e-5f

typedef _Float16 half8 __attribute__((ext_vector_type(8)));
typedef _Float16 half4 __attribute__((ext_vector_type(4)));
typedef _Float16 half2v __attribute__((ext_vector_type(2)));
typedef float f32x4 __attribute__((ext_vector_type(4)));

__device__ __forceinline__ void gld_lds16(const void* g, void* s) {
  __builtin_amdgcn_global_load_lds(
      (const __attribute__((address_space(1))) void*)g,
      (__attribute__((address_space(3))) void*)s, 16, 0, 0);
}

// ---------------------------------------------------------------------------
// fp16 MFMA GEMM: C[M,Nn] = A[M,K]fp16 @ B[Nn,K]fp16^T  (NT)
// 128x128 tile, BK=32, 256 threads = 4 waves (2x2), 4x4 16x16x32 frags/wave.
// ---------------------------------------------------------------------------
template <int OUT16>
__global__ __launch_bounds__(256) void k_mfma_gemm(
    const _Float16* __restrict__ A, const _Float16* __restrict__ B,
    float* __restrict__ Cf, _Float16* __restrict__ Ch,
    int M, int Nn, int K) {
  __shared__ __align__(16) _Float16 sA[128 * 32];
  __shared__ __align__(16) _Float16 sB[128 * 32];
  const int tid = threadIdx.x;
  const int lane = tid & 63, w = tid >> 6;
  const int wm = w >> 1, wn = w & 1;
  const int row0 = blockIdx.y * 128, col0 = blockIdx.x * 128;

  const int r_loc = lane >> 2;       // 0..15
  const int j8 = (lane & 3) * 8;     // half offset within BK=32
  const _Float16* gA = A + (size_t)(row0 + w * 32 + r_loc) * K + j8;
  const _Float16* gB = B + (size_t)(col0 + w * 32 + r_loc) * K + j8;
  _Float16* sAw = sA + (w * 32) * 32;
  _Float16* sBw = sB + (w * 32) * 32;

  const int fr = lane & 15, kb = lane >> 4;
  const _Float16* pA = sA + ((size_t)(wm * 64 + fr) * 32 + kb * 8);
  const _Float16* pB = sB + ((size_t)(wn * 64 + fr) * 32 + kb * 8);

  f32x4 acc[4][4] = {};
  const int KT = K / 32;

  {
    gld_lds16(gA, sAw);
    gld_lds16(gA + (size_t)16 * K, sAw + 16 * 32);
    gld_lds16(gB, sBw);
    gld_lds16(gB + (size_t)16 * K, sBw + 16 * 32);
  }
  for (int kt = 0; kt < KT; ++kt) {
    __syncthreads();
    half8 af[4], bf[4];
#pragma unroll
    for (int i = 0; i < 4; ++i) af[i] = *(const half8*)(pA + i * 16 * 32);
#pragma unroll
    for (int j = 0; j < 4; ++j) bf[j] = *(const half8*)(pB + j * 16 * 32);
    __syncthreads();
    if (kt + 1 < KT) {
      const _Float16* ga = gA + (size_t)(kt + 1) * 32;
      const _Float16* gb = gB + (size_t)(kt + 1) * 32;
      gld_lds16(ga, sAw);
      gld_lds16(ga + (size_t)16 * K, sAw + 16 * 32);
      gld_lds16(gb, sBw);
      gld_lds16(gb + (size_t)16 * K, sBw + 16 * 32);
    }
#pragma unroll
    for (int i = 0; i < 4; ++i)
#pragma unroll
      for (int j = 0; j < 4; ++j)
        acc[i][j] =
            __builtin_amdgcn_mfma_f32_16x16x32_f16(af[i], bf[j], acc[i][j], 0, 0, 0);
  }

  // C/D layout: col = lane&15, row = (lane>>4)*4 + reg
  const int orow = row0 + wm * 64 + kb * 4;
  const int ocol = col0 + wn * 64 + fr;
#pragma unroll
  for (int i = 0; i < 4; ++i) {
#pragma unroll
    for (int r = 0; r < 4; ++r) {
      const int rr = orow + i * 16 + r;
      if (rr >= M) continue;
#pragma unroll
      for (int j = 0; j < 4; ++j) {
        if (OUT16) Ch[(size_t)rr * Nn + ocol + j * 16] = (_Float16)acc[i][j][r];
        else       Cf[(size_t)rr * Nn + ocol + j * 16] = acc[i][j][r];
      }
    }
  }
}

// ---------------------------------------------------------------------------
// fp32 -> fp16 conversion with K padding (zeros for k >= K)
// ---------------------------------------------------------------------------
__global__ __launch_bounds__(256) void k_cvt(const float* __restrict__ in,
                                             _Float16* __restrict__ out,
                                             int M, int K, int Kpad) {
  const int idx = blockIdx.x * 256 + threadIdx.x;
  const int kp2 = Kpad >> 1;
  if (idx >= M * kp2) return;
  const int r = idx / kp2, c2 = (idx % kp2) * 2;
  const float vx = (c2 < K) ? in[(size_t)r * K + c2] : 0.f;
  const float vy = (c2 + 1 < K) ? in[(size_t)r * K + c2 + 1] : 0.f;
  out[(size_t)r * Kpad + c2] = (_Float16)vx;
  out[(size_t)r * Kpad + c2 + 1] = (_Float16)vy;
}

// ---------------------------------------------------------------------------
// Fold bias+BN into per-column scale/shift: val = acc*idn*A[c] + B[c], then ELU
// ---------------------------------------------------------------------------
__global__ __launch_bounds__(256) void k_bnp(
    const float* __restrict__ bias, const float* __restrict__ gg,
    const float* __restrict__ be, const float* __restrict__ mm,
    const float* __restrict__ vv, float* __restrict__ A,
    float* __restrict__ B, int C) {
  const int c = blockIdx.x * 256 + threadIdx.x;
  if (c >= C) return;
  if (gg) {
    const float rs = rsqrtf(vv[c] + BN_EPS) * gg[c];
    A[c] = rs;
    B[c] = (bias[c] - mm[c]) * rs + be[c];
  } else {
    A[c] = 1.f;
    B[c] = bias[c];
  }
}

// ---------------------------------------------------------------------------
// Fused MLP head: out = fc2( relu( fc1(h) ) ), 8 nodes per block.
// ---------------------------------------------------------------------------
#define MLP_NPB 8
__global__ __launch_bounds__(256) void k_mlp(
    const float* __restrict__ h, const float* __restrict__ W1,
    const float* __restrict__ b1, const float* __restrict__ W2,
    const float* __restrict__ b2, float* __restrict__ out) {
  __shared__ float sh[MLP_NPB * 256];   // 8 input rows (8 KB)
  __shared__ float sy[MLP_NPB][132];    // relu(fc1) padded (4.2 KB)
  const int tid = threadIdx.x;
  const int n0 = blockIdx.x * MLP_NPB;
  {
    const float4* src = (const float4*)(h + (size_t)n0 * 256);
    float4* dst = (float4*)sh;
    dst[tid] = src[tid];
    dst[tid + 256] = src[tid + 256];
  }
  __syncthreads();
  const int j = tid & 127;   // fc1 output index
  const int g = tid >> 7;    // node group: nodes g*4 .. g*4+3
  const float bj = b1[j];
  float a0 = bj, a1 = bj, a2 = bj, a3 = bj;
  const float4* wrow = (const float4*)(W1 + (size_t)j * 256);
  const float4* h0 = (const float4*)(sh + (g * 4 + 0) * 256);
  const float4* h1 = (const float4*)(sh + (g * 4 + 1) * 256);
  const float4* h2 = (const float4*)(sh + (g * 4 + 2) * 256);
  const float4* h3 = (const float4*)(sh + (g * 4 + 3) * 256);
#pragma unroll 8
  for (int k = 0; k < 64; ++k) {
    const float4 w = wrow[k];
    const float4 v0 = h0[k], v1 = h1[k], v2 = h2[k], v3 = h3[k];
    a0 += w.x * v0.x + w.y * v0.y + w.z * v0.z + w.w * v0.w;
    a1 += w.x * v1.x + w.y * v1.y + w.z * v1.z + w.w * v1.w;
    a2 += w.x * v2.x + w.y * v2.y + w.z * v2.z + w.w * v2.w;
    a3 += w.x * v3.x + w.y * v3.y + w.z * v3.z + w.w * v3.w;
  }
  sy[g * 4 + 0][j] = a0 > 0.f ? a0 : 0.f;
  sy[g * 4 + 1][j] = a1 > 0.f ? a1 : 0.f;
  sy[g * 4 + 2][j] = a2 > 0.f ? a2 : 0.f;
  sy[g * 4 + 3][j] = a3 > 0.f ? a3 : 0.f;
  __syncthreads();
  if (tid < MLP_NPB * NCLS) {  // 48 threads
    const int n = tid / NCLS, c = tid % NCLS;
    float s = b2[c];
    const float* w2 = W2 + c * 128;
#pragma unroll 8
    for (int k = 0; k < 128; ++k) s += sy[n][k] * w2[k];
    out[(size_t)(n0 + n) * NCLS + c] = s;
  }
}

// ---------------------------------------------------------------------------
// alpha_s[n,h] = <h[n,h,:], a_src[h,:]> from fp16 h. Block = HH*64.
// ---------------------------------------------------------------------------
template <int HH>
__global__ __launch_bounds__(HH * 64) void k_alpha(
    const _Float16* __restrict__ h, const float* __restrict__ a_src,
    const float* __restrict__ a_dst, float* __restrict__ as_,
    float* __restrict__ ad_) {
  const int n = blockIdx.x;
  const int tid = threadIdx.x;
  const int head = tid >> 6;
  const int lane = tid & 63;
  const half4 hv = *(const half4*)(h + (size_t)n * HH * DH + head * DH + lane * 4);
  const float4 sv = *(reinterpret_cast<const float4*>(a_src + head * DH) + lane);
  const float4 dv = *(reinterpret_cast<const float4*>(a_dst + head * DH) + lane);
  const float h0 = (float)hv[0], h1 = (float)hv[1], h2 = (float)hv[2],
              h3 = (float)hv[3];
  float s1 = h0 * sv.x + h1 * sv.y + h2 * sv.z + h3 * sv.w;
  float s2 = h0 * dv.x + h1 * dv.y + h2 * dv.z + h3 * dv.w;
#pragma unroll
  for (int off = 32; off > 0; off >>= 1) {
    s1 += __shfl_down(s1, off);
    s2 += __shfl_down(s2, off);
  }
  if (lane == 0) {
    as_[n * HH + head] = s1;
    ad_[n * HH + head] = s2;
  }
}

// ---------------------------------------------------------------------------
// Per edge: all heads. w = exp(leaky_relu(as[src]+ad[dst])).
// ewc layout: PLANES [head][ETOT] in CSR slot order (contiguous per-head
// reads in the sliced aggregation).
// ---------------------------------------------------------------------------
template <int HH>
__global__ __launch_bounds__(256) void k_edge(
    const int* __restrict__ ei, const int* __restrict__ einv,
    float* __restrict__ ewc, float* __restrict__ den,
    const float* __restrict__ as_, const float* __restrict__ ad_) {
  const int e = blockIdx.x * 256 + threadIdx.x;
  if (e >= ETOT) return;
  int s, t;
  if (e < N_EDGES) { s = ei[e]; t = ei[N_EDGES + e]; }
  else             { s = t = e - N_EDGES; }
  const int pos = einv[e];
#pragma unroll
  for (int hh = 0; hh < HH; ++hh) {
    float x = as_[s * HH + hh] + ad_[t * HH + hh];
    x = x > 0.f ? x : 0.2f * x;
    const float w = expf(x);
    ewc[(size_t)hh * ETOT + pos] = w;
    atomicAdd(&den[t * HH + hh], w);
  }
}

// ---------------------------------------------------------------------------
// CSR build
// ---------------------------------------------------------------------------
__global__ __launch_bounds__(256) void k_count(const int* __restrict__ ei,
                                               int* __restrict__ cnt) {
  const int e = blockIdx.x * 256 + threadIdx.x;
  if (e >= ETOT) return;
  const int t = (e < N_EDGES) ? ei[N_EDGES + e] : (e - N_EDGES);
  atomicAdd(&cnt[t], 1);
}

__global__ __launch_bounds__(256) void k_scan(const int* __restrict__ cnt,
                                              int* __restrict__ rowptr) {
  __shared__ int part[256];
  const int tid = threadIdx.x;
  const int chunk = (N_NODES + 255) / 256;  // 40
  const int b = tid * chunk;
  int sum = 0;
  for (int i = 0; i < chunk; i++) {
    const int idx = b + i;
    if (idx < N_NODES) sum += cnt[idx];
  }
  part[tid] = sum;
  __syncthreads();
  for (int off = 1; off < 256; off <<= 1) {
    int t2 = (tid >= off) ? part[tid - off] : 0;
    __syncthreads();
    part[tid] += t2;
    __syncthreads();
  }
  int run = part[tid] - sum;
  for (int i = 0; i < chunk; i++) {
    const int idx = b + i;
    if (idx < N_NODES) {
      rowptr[idx] = run;
      run += cnt[idx];
    }
  }
  if (tid == 255) rowptr[N_NODES] = part[255];
}

__global__ __launch_bounds__(256) void k_fill(
    const int* __restrict__ ei, const int* __restrict__ rowptr,
    int* __restrict__ fill, int* __restrict__ csr_src,
    int* __restrict__ einv) {
  const int e = blockIdx.x * 256 + threadIdx.x;
  if (e >= ETOT) return;
  int s, t;
  if (e < N_EDGES) { s = ei[e]; t = ei[N_EDGES + e]; }
  else             { s = t = e - N_EDGES; }
  const int pos = rowptr[t] + atomicAdd(&fill[t], 1);
  csr_src[pos] = s;
  einv[e] = pos;
}

// ---------------------------------------------------------------------------
// HH=4 aggregation, XCD-sliced (round 9): grid = N*8, block = 64.
// Block b: node n = b>>3, column group g = b&7 (128 cols). Consecutive
// blockIdx round-robins across the 8 XCDs, so one XCD serves one column
// group -> its h working set = 10000 x 128 x 2B = 2.56 MB < 4 MB L2.
// Gathers become L2 hits instead of L3 misses (R6/7/8: FETCH pinned at
// 144 MB, L2-miss path ~1.8 TB/s was the binding resource).
// Epilogue: val = ELU(acc*idn*A[c] + B[c]) with bias+BN folded into A,B.
// ---------------------------------------------------------------------------
__global__ __launch_bounds__(64) void k_agg4s(
    const _Float16* __restrict__ h, const int* __restrict__ rowptr,
    const int* __restrict__ csr_src, const float* __restrict__ ewc,
    const float* __restrict__ den, const float* __restrict__ Af,
    const float* __restrict__ Bf, _Float16* __restrict__ outh) {
  const int b = blockIdx.x;
  const int g = b & 7;            // column group -> XCD
  const int n = b >> 3;           // node
  const int lane = threadIdx.x;   // 0..63
  const int c0 = g * 128 + lane * 2;
  const int head = g >> 1;
  __shared__ int s_src[64];
  __shared__ float s_al[64];
  const float idn = 1.f / (den[n * 4 + head] + 1e-16f);
  const float* ewh = ewc + (size_t)head * ETOT;
  float ax = 0.f, ay = 0.f;
  const int beg = rowptr[n], end = rowptr[n + 1];
  for (int base = beg; base < end; base += 64) {
    const int cnt = min(64, end - base);
    __syncthreads();
    if (lane < cnt) {
      s_src[lane] = csr_src[base + lane];
      s_al[lane] = ewh[base + lane];
    }
    __syncthreads();
    int j = 0;
    const int nfull = cnt & ~7;
    for (; j < nfull; j += 8) {
      float w[8];
      half2v v[8];
#pragma unroll
      for (int u = 0; u < 8; ++u) {
        w[u] = s_al[j + u];
        v[u] = *(const half2v*)(h + (size_t)s_src[j + u] * C1 + c0);
      }
#pragma unroll
      for (int u = 0; u < 8; ++u) {
        ax += (float)v[u][0] * w[u];
        ay += (float)v[u][1] * w[u];
      }
    }
    for (; j < cnt; ++j) {
      const float w0 = s_al[j];
      const half2v v = *(const half2v*)(h + (size_t)s_src[j] * C1 + c0);
      ax += (float)v[0] * w0;
      ay += (float)v[1] * w0;
    }
  }
  float r0 = ax * idn * Af[c0] + Bf[c0];
  float r1 = ay * idn * Af[c0 + 1] + Bf[c0 + 1];
  r0 = r0 > 0.f ? r0 : expm1f(r0);  // ELU
  r1 = r1 > 0.f ? r1 : expm1f(r1);
  half2v ov;
  ov[0] = (_Float16)r0;
  ov[1] = (_Float16)r1;
  *(half2v*)(outh + (size_t)n * C1 + c0) = ov;
}

// ---------------------------------------------------------------------------
// HH=1 aggregation (layer 3): 64 thr, half4, fp32 out, ELU. (ewc plane 0)
// ---------------------------------------------------------------------------
__global__ __launch_bounds__(64) void k_agg1(
    const _Float16* __restrict__ h, const int* __restrict__ rowptr,
    const int* __restrict__ csr_src, const float* __restrict__ ewc,
    const float* __restrict__ den, const float* __restrict__ bias,
    float* __restrict__ outf) {
  const int n = blockIdx.x;
  const int tid = threadIdx.x;
  const int c0 = tid * 4;
  __shared__ int s_src[64];
  __shared__ float s_al[64];
  const float idn = 1.f / (den[n] + 1e-16f);
  float acc[4] = {};
  const int beg = rowptr[n], end = rowptr[n + 1];
  for (int base = beg; base < end; base += 64) {
    const int cnt = min(64, end - base);
    __syncthreads();
    if (tid < cnt) {
      s_src[tid] = csr_src[base + tid];
      s_al[tid] = ewc[base + tid];
    }
    __syncthreads();
    int j = 0;
    const int nfull = cnt & ~7;
    for (; j < nfull; j += 8) {
      float w[8];
      half4 v[8];
#pragma unroll
      for (int u = 0; u < 8; ++u) {
        w[u] = s_al[j + u];
        v[u] = *(const half4*)(h + (size_t)s_src[j + u] * DH + c0);
      }
#pragma unroll
      for (int u = 0; u < 8; ++u)
#pragma unroll
        for (int i = 0; i < 4; ++i) acc[i] += (float)v[u][i] * w[u];
    }
    for (; j < cnt; ++j) {
      const float w0 = s_al[j];
      const half4 v = *(const half4*)(h + (size_t)s_src[j] * DH + c0);
#pragma unroll
      for (int i = 0; i < 4; ++i) acc[i] += (float)v[i] * w0;
    }
  }
#pragma unroll
  for (int i = 0; i < 4; i++) {
    const int c = c0 + i;
    float val = acc[i] * idn + bias[c];
    val = val > 0.f ? val : expm1f(val);  // ELU
    outf[(size_t)n * DH + c] = val;
  }
}

// ---------------------------------------------------------------------------
extern "C" void kernel_launch(void* const* d_in, const int* in_sizes, int n_in,
                              void* d_out, int out_size, void* d_ws,
                              size_t ws_size, hipStream_t stream) {
  const float* x    = (const float*)d_in[0];
  const int*   ei   = (const int*)d_in[1];
  const float* W1   = (const float*)d_in[2];
  const float* a1s  = (const float*)d_in[3];
  const float* a1d  = (const float*)d_in[4];
  const float* b1   = (const float*)d_in[5];
  const float* W2   = (const float*)d_in[6];
  const float* a2s  = (const float*)d_in[7];
  const float* a2d  = (const float*)d_in[8];
  const float* b2   = (const float*)d_in[9];
  const float* W3   = (const float*)d_in[10];
  const float* a3s  = (const float*)d_in[11];
  const float* a3d  = (const float*)d_in[12];
  const float* b3   = (const float*)d_in[13];
  const float* g1   = (const float*)d_in[14];
  const float* be1  = (const float*)d_in[15];
  const float* m1   = (const float*)d_in[16];
  const float* v1   = (const float*)d_in[17];
  const float* g2   = (const float*)d_in[18];
  const float* be2  = (const float*)d_in[19];
  const float* m2   = (const float*)d_in[20];
  const float* v2   = (const float*)d_in[21];
  const float* fc1W = (const float*)d_in[22];
  const float* fc1b = (const float*)d_in[23];
  const float* fc2W = (const float*)d_in[24];
  const float* fc2b = (const float*)d_in[25];
  float* out = (float*)d_out;

  char* p = (char*)d_ws;
  auto alloc = [&](size_t bytes) -> void* {
    void* r = (void*)p;
    p += (bytes + 255) & ~(size_t)255;
    return r;
  };
  _Float16* hA     = (_Float16*)alloc((size_t)M_PAD * C1 * 2);  // GEMM input (holds xh first)
  _Float16* hG     = (_Float16*)alloc((size_t)M_PAD * C1 * 2);  // GEMM output
  _Float16* wh     = (_Float16*)alloc((size_t)C1 * C1 * 2);
  float*    buf1   = (float*)alloc((size_t)N_NODES * DH * 4);   // agg3 out -> MLP in
  float*    as_    = (float*)alloc((size_t)N_NODES * HEADS * 4);
  float*    ad_    = (float*)alloc((size_t)N_NODES * HEADS * 4);
  float*    den    = (float*)alloc((size_t)N_NODES * HEADS * 4);
  float*    ewc    = (float*)alloc((size_t)ETOT * HEADS * 4);   // [head][ETOT]
  float*    Afold  = (float*)alloc((size_t)C1 * 4);
  float*    Bfold  = (float*)alloc((size_t)C1 * 4);
  int*      rowptr = (int*)alloc((size_t)(N_NODES + 1) * 4);
  int*      cnt    = (int*)alloc((size_t)N_NODES * 4);
  int*      csrS   = (int*)alloc((size_t)ETOT * 4);
  int*      einv   = (int*)alloc((size_t)ETOT * 4);

  const int eb = (ETOT + 255) / 256;
  _Float16* xh = hA;  // alias: [M_PAD][K1PAD]

  // ---- CSR build (graph identical for all three layers) ----
  hipMemsetAsync(cnt, 0, (size_t)N_NODES * 4, stream);
  k_count<<<eb, 256, 0, stream>>>(ei, cnt);
  k_scan<<<1, 256, 0, stream>>>(cnt, rowptr);
  hipMemsetAsync(cnt, 0, (size_t)N_NODES * 4, stream);
  k_fill<<<eb, 256, 0, stream>>>(ei, rowptr, cnt, csrS, einv);

  // ---- Layer 1: GATConv(300 -> 4x256) + BN1 + ELU ----
  k_cvt<<<(N_NODES * (K1PAD / 2) + 255) / 256, 256, 0, stream>>>(
      x, xh, N_NODES, F_INDIM, K1PAD);
  k_cvt<<<(C1 * (K1PAD / 2) + 255) / 256, 256, 0, stream>>>(
      W1, wh, C1, F_INDIM, K1PAD);
  k_mfma_gemm<1><<<dim3(C1 / 128, M_PAD / 128), 256, 0, stream>>>(
      xh, wh, nullptr, hG, N_NODES, C1, K1PAD);
  k_alpha<4><<<N_NODES, 256, 0, stream>>>(hG, a1s, a1d, as_, ad_);
  hipMemsetAsync(den, 0, (size_t)N_NODES * HEADS * 4, stream);
  k_edge<4><<<eb, 256, 0, stream>>>(ei, einv, ewc, den, as_, ad_);
  k_bnp<<<(C1 + 255) / 256, 256, 0, stream>>>(b1, g1, be1, m1, v1,
                                              Afold, Bfold, C1);
  k_agg4s<<<N_NODES * 8, 64, 0, stream>>>(hG, rowptr, csrS, ewc, den,
                                          Afold, Bfold, hA);

  // ---- Layer 2: GATConv(1024 -> 4x256) + BN2 + ELU ----
  k_cvt<<<(C1 * (C1 / 2) + 255) / 256, 256, 0, stream>>>(W2, wh, C1, C1, C1);
  k_mfma_gemm<1><<<dim3(C1 / 128, M_PAD / 128), 256, 0, stream>>>(
      hA, wh, nullptr, hG, N_NODES, C1, C1);
  k_alpha<4><<<N_NODES, 256, 0, stream>>>(hG, a2s, a2d, as_, ad_);
  hipMemsetAsync(den, 0, (size_t)N_NODES * HEADS * 4, stream);
  k_edge<4><<<eb, 256, 0, stream>>>(ei, einv, ewc, den, as_, ad_);
  k_bnp<<<(C1 + 255) / 256, 256, 0, stream>>>(b2, g2, be2, m2, v2,
                                              Afold, Bfold, C1);
  k_agg4s<<<N_NODES * 8, 64, 0, stream>>>(hG, rowptr, csrS, ewc, den,
                                          Afold, Bfold, hA);

  // ---- Layer 3: GATConv(1024 -> 256, heads=1) + ELU ----
  k_cvt<<<(DH * (C1 / 2) + 255) / 256, 256, 0, stream>>>(W3, wh, DH, C1, C1);
  k_mfma_gemm<1><<<dim3(DH / 128, M_PAD / 128), 256, 0, stream>>>(
      hA, wh, nullptr, hG, N_NODES, DH, C1);
  k_alpha<1><<<N_NODES, 64, 0, stream>>>(hG, a3s, a3d, as_, ad_);
  hipMemsetAsync(den, 0, (size_t)N_NODES * 4, stream);
  k_edge<1><<<eb, 256, 0, stream>>>(ei, einv, ewc, den, as_, ad_);
  k_agg1<<<N_NODES, 64, 0, stream>>>(hG, rowptr, csrS, ewc, den, b3, buf1);

  // ---- Fused MLP head ----
  k_mlp<<<N_NODES / MLP_NPB, 256, 0, stream>>>(buf1, fc1W, fc1b, fc2W, fc2b,
                                               out);
}

// Round 12
// 468.929 us; speedup vs baseline: 1.3368x; 1.0338x over previous
//
#include <hip/hip_runtime.h>
#include <cstdint>
#include <cstddef>

#define N_NODES 10000
#define M_PAD   10112            // 79 * 128
#define N_EDGES 160000
#define ETOT    (N_EDGES + N_NODES)   // with self-loops
#define F_INDIM 300
#define K1PAD   320              // F_INDIM padded to mult of 32
#define HEADS   4
#define DH      256
#define C1      (HEADS * DH)     // 1024
#define NCLS    6
#define BN_EPS  1e-5f

typedef _Float16 half8 __attribute__((ext_vector_type(8)));
typedef _Float16 half4 __attribute__((ext_vector_type(4)));
typedef _Float16 half2v __attribute__((ext_vector_type(2)));
typedef float f32x4 __attribute__((ext_vector_type(4)));

__device__ __forceinline__ void gld_lds16(const void* g, void* s) {
  __builtin_amdgcn_global_load_lds(
      (const __attribute__((address_space(1))) void*)g,
      (__attribute__((address_space(3))) void*)s, 16, 0, 0);
}

// ---------------------------------------------------------------------------
// fp16 MFMA GEMM: C[M,Nn] = act(A[M,K]fp16 @ B[Nn,K]fp16^T + bias)  (NT)
// 128x128 tile, BK=32, 256 threads = 4 waves (2x2), 4x4 16x16x32 frags/wave.
// OUT16: fp16 vs fp32 output. ACT=1: ReLU. bias nullable (fp32).
// ---------------------------------------------------------------------------
template <int OUT16, int ACT>
__global__ __launch_bounds__(256) void k_mfma_gemm(
    const _Float16* __restrict__ A, const _Float16* __restrict__ B,
    const float* __restrict__ bias, float* __restrict__ Cf,
    _Float16* __restrict__ Ch, int M, int Nn, int K) {
  __shared__ __align__(16) _Float16 sA[128 * 32];
  __shared__ __align__(16) _Float16 sB[128 * 32];
  const int tid = threadIdx.x;
  const int lane = tid & 63, w = tid >> 6;
  const int wm = w >> 1, wn = w & 1;
  const int row0 = blockIdx.y * 128, col0 = blockIdx.x * 128;

  const int r_loc = lane >> 2;       // 0..15
  const int j8 = (lane & 3) * 8;     // half offset within BK=32
  const _Float16* gA = A + (size_t)(row0 + w * 32 + r_loc) * K + j8;
  const _Float16* gB = B + (size_t)(col0 + w * 32 + r_loc) * K + j8;
  _Float16* sAw = sA + (w * 32) * 32;
  _Float16* sBw = sB + (w * 32) * 32;

  const int fr = lane & 15, kb = lane >> 4;
  const _Float16* pA = sA + ((size_t)(wm * 64 + fr) * 32 + kb * 8);
  const _Float16* pB = sB + ((size_t)(wn * 64 + fr) * 32 + kb * 8);

  f32x4 acc[4][4] = {};
  const int KT = K / 32;

  {
    gld_lds16(gA, sAw);
    gld_lds16(gA + (size_t)16 * K, sAw + 16 * 32);
    gld_lds16(gB, sBw);
    gld_lds16(gB + (size_t)16 * K, sBw + 16 * 32);
  }
  for (int kt = 0; kt < KT; ++kt) {
    __syncthreads();
    half8 af[4], bf[4];
#pragma unroll
    for (int i = 0; i < 4; ++i) af[i] = *(const half8*)(pA + i * 16 * 32);
#pragma unroll
    for (int j = 0; j < 4; ++j) bf[j] = *(const half8*)(pB + j * 16 * 32);
    __syncthreads();
    if (kt + 1 < KT) {
      const _Float16* ga = gA + (size_t)(kt + 1) * 32;
      const _Float16* gb = gB + (size_t)(kt + 1) * 32;
      gld_lds16(ga, sAw);
      gld_lds16(ga + (size_t)16 * K, sAw + 16 * 32);
      gld_lds16(gb, sBw);
      gld_lds16(gb + (size_t)16 * K, sBw + 16 * 32);
    }
#pragma unroll
    for (int i = 0; i < 4; ++i)
#pragma unroll
      for (int j = 0; j < 4; ++j)
        acc[i][j] =
            __builtin_amdgcn_mfma_f32_16x16x32_f16(af[i], bf[j], acc[i][j], 0, 0, 0);
  }

  // C/D layout: col = lane&15, row = (lane>>4)*4 + reg
  const int orow = row0 + wm * 64 + kb * 4;
  const int ocol = col0 + wn * 64 + fr;
#pragma unroll
  for (int i = 0; i < 4; ++i) {
#pragma unroll
    for (int r = 0; r < 4; ++r) {
      const int rr = orow + i * 16 + r;
      if (rr >= M) continue;
#pragma unroll
      for (int j = 0; j < 4; ++j) {
        float v = acc[i][j][r];
        if (bias) v += bias[ocol + j * 16];
        if (ACT == 1) v = v > 0.f ? v : 0.f;
        if (OUT16) Ch[(size_t)rr * Nn + ocol + j * 16] = (_Float16)v;
        else       Cf[(size_t)rr * Nn + ocol + j * 16] = v;
      }
    }
  }
}

// ---------------------------------------------------------------------------
// fp32 -> fp16 conversion with K padding (zeros for k >= K)
// ---------------------------------------------------------------------------
__global__ __launch_bounds__(256) void k_cvt(const float* __restrict__ in,
                                             _Float16* __restrict__ out,
                                             int M, int K, int Kpad) {
  const int idx = blockIdx.x * 256 + threadIdx.x;
  const int kp2 = Kpad >> 1;
  if (idx >= M * kp2) return;
  const int r = idx / kp2, c2 = (idx % kp2) * 2;
  const float vx = (c2 < K) ? in[(size_t)r * K + c2] : 0.f;
  const float vy = (c2 + 1 < K) ? in[(size_t)r * K + c2 + 1] : 0.f;
  out[(size_t)r * Kpad + c2] = (_Float16)vx;
  out[(size_t)r * Kpad + c2 + 1] = (_Float16)vy;
}

// ---------------------------------------------------------------------------
// Fold bias+BN into per-column scale/shift: val = acc*idn*A[c] + B[c], then ELU
// ---------------------------------------------------------------------------
__global__ __launch_bounds__(256) void k_bnp(
    const float* __restrict__ bias, const float* __restrict__ gg,
    const float* __restrict__ be, const float* __restrict__ mm,
    const float* __restrict__ vv, float* __restrict__ A,
    float* __restrict__ B, int C) {
  const int c = blockIdx.x * 256 + threadIdx.x;
  if (c >= C) return;
  if (gg) {
    const float rs = rsqrtf(vv[c] + BN_EPS) * gg[c];
    A[c] = rs;
    B[c] = (bias[c] - mm[c]) * rs + be[c];
  } else {
    A[c] = 1.f;
    B[c] = bias[c];
  }
}

// ---------------------------------------------------------------------------
// fc2 epilogue: out[n,c] = <relu_fc1[n,:], W2[c,:]> + b2[c]. 8 nodes/block.
// Stage y coalesced (float4/thread) into padded LDS; 48 threads compute.
// (Old k_mlp's fc1 was 45.6us: per-thread W1 rows = 64-line uncoalesced
//  wave-loads, request-rate bound. fc1 now runs on the MFMA GEMM.)
// ---------------------------------------------------------------------------
__global__ __launch_bounds__(256) void k_fc2(
    const float* __restrict__ y, const float* __restrict__ W2,
    const float* __restrict__ b2, float* __restrict__ out) {
  __shared__ float sy[8][132];
  const int tid = threadIdx.x;
  const int n0 = blockIdx.x * 8;
  const float4 v = ((const float4*)(y + (size_t)n0 * 128))[tid];
  const int r = tid >> 5, c4 = (tid & 31) * 4;
  sy[r][c4 + 0] = v.x;
  sy[r][c4 + 1] = v.y;
  sy[r][c4 + 2] = v.z;
  sy[r][c4 + 3] = v.w;
  __syncthreads();
  if (tid < 8 * NCLS) {  // 48 threads
    const int n = tid / NCLS, c = tid % NCLS;
    float s = b2[c];
    const float* w2 = W2 + c * 128;
#pragma unroll 8
    for (int k = 0; k < 128; ++k) s += sy[n][k] * w2[k];
    out[(size_t)(n0 + n) * NCLS + c] = s;
  }
}

// ---------------------------------------------------------------------------
// alpha_s[n,h] = <h[n,h,:], a_src[h,:]> from fp16 h. Block = HH*64.
// ---------------------------------------------------------------------------
template <int HH>
__global__ __launch_bounds__(HH * 64) void k_alpha(
    const _Float16* __restrict__ h, const float* __restrict__ a_src,
    const float* __restrict__ a_dst, float* __restrict__ as_,
    float* __restrict__ ad_) {
  const int n = blockIdx.x;
  const int tid = threadIdx.x;
  const int head = tid >> 6;
  const int lane = tid & 63;
  const half4 hv = *(const half4*)(h + (size_t)n * HH * DH + head * DH + lane * 4);
  const float4 sv = *(reinterpret_cast<const float4*>(a_src + head * DH) + lane);
  const float4 dv = *(reinterpret_cast<const float4*>(a_dst + head * DH) + lane);
  const float h0 = (float)hv[0], h1 = (float)hv[1], h2 = (float)hv[2],
              h3 = (float)hv[3];
  float s1 = h0 * sv.x + h1 * sv.y + h2 * sv.z + h3 * sv.w;
  float s2 = h0 * dv.x + h1 * dv.y + h2 * dv.z + h3 * dv.w;
#pragma unroll
  for (int off = 32; off > 0; off >>= 1) {
    s1 += __shfl_down(s1, off);
    s2 += __shfl_down(s2, off);
  }
  if (lane == 0) {
    as_[n * HH + head] = s1;
    ad_[n * HH + head] = s2;
  }
}

// ---------------------------------------------------------------------------
// Per edge: all heads. w = exp(leaky_relu(as[src]+ad[dst])).
// ewc layout: PLANES [head][ETOT] in CSR slot order.
// ---------------------------------------------------------------------------
template <int HH>
__global__ __launch_bounds__(256) void k_edge(
    const int* __restrict__ ei, const int* __restrict__ einv,
    float* __restrict__ ewc, float* __restrict__ den,
    const float* __restrict__ as_, const float* __restrict__ ad_) {
  const int e = blockIdx.x * 256 + threadIdx.x;
  if (e >= ETOT) return;
  int s, t;
  if (e < N_EDGES) { s = ei[e]; t = ei[N_EDGES + e]; }
  else             { s = t = e - N_EDGES; }
  const int pos = einv[e];
#pragma unroll
  for (int hh = 0; hh < HH; ++hh) {
    float x = as_[s * HH + hh] + ad_[t * HH + hh];
    x = x > 0.f ? x : 0.2f * x;
    const float w = expf(x);
    ewc[(size_t)hh * ETOT + pos] = w;
    atomicAdd(&den[t * HH + hh], w);
  }
}

// ---------------------------------------------------------------------------
// CSR build
// ---------------------------------------------------------------------------
__global__ __launch_bounds__(256) void k_count(const int* __restrict__ ei,
                                               int* __restrict__ cnt) {
  const int e = blockIdx.x * 256 + threadIdx.x;
  if (e >= ETOT) return;
  const int t = (e < N_EDGES) ? ei[N_EDGES + e] : (e - N_EDGES);
  atomicAdd(&cnt[t], 1);
}

__global__ __launch_bounds__(256) void k_scan(const int* __restrict__ cnt,
                                              int* __restrict__ rowptr) {
  __shared__ int part[256];
  const int tid = threadIdx.x;
  const int chunk = (N_NODES + 255) / 256;  // 40
  const int b = tid * chunk;
  int sum = 0;
  for (int i = 0; i < chunk; i++) {
    const int idx = b + i;
    if (idx < N_NODES) sum += cnt[idx];
  }
  part[tid] = sum;
  __syncthreads();
  for (int off = 1; off < 256; off <<= 1) {
    int t2 = (tid >= off) ? part[tid - off] : 0;
    __syncthreads();
    part[tid] += t2;
    __syncthreads();
  }
  int run = part[tid] - sum;
  for (int i = 0; i < chunk; i++) {
    const int idx = b + i;
    if (idx < N_NODES) {
      rowptr[idx] = run;
      run += cnt[idx];
    }
  }
  if (tid == 255) rowptr[N_NODES] = part[255];
}

__global__ __launch_bounds__(256) void k_fill(
    const int* __restrict__ ei, const int* __restrict__ rowptr,
    int* __restrict__ fill, int* __restrict__ csr_src,
    int* __restrict__ einv) {
  const int e = blockIdx.x * 256 + threadIdx.x;
  if (e >= ETOT) return;
  int s, t;
  if (e < N_EDGES) { s = ei[e]; t = ei[N_EDGES + e]; }
  else             { s = t = e - N_EDGES; }
  const int pos = rowptr[t] + atomicAdd(&fill[t], 1);
  csr_src[pos] = s;
  einv[e] = pos;
}

// ---------------------------------------------------------------------------
// HH=4 aggregation, XCD-sliced: grid = N*8, block = 64. Block b: node b>>3,
// column group b&7 -> one XCD's 2.56MB h-slice fits its 4MB L2 (verified
// R11: total -65us, agg4s out of top-5).
// ---------------------------------------------------------------------------
__global__ __launch_bounds__(64) void k_agg4s(
    const _Float16* __restrict__ h, const int* __restrict__ rowptr,
    const int* __restrict__ csr_src, const float* __restrict__ ewc,
    const float* __restrict__ den, const float* __restrict__ Af,
    const float* __restrict__ Bf, _Float16* __restrict__ outh) {
  const int b = blockIdx.x;
  const int g = b & 7;            // column group -> XCD
  const int n = b >> 3;           // node
  const int lane = threadIdx.x;   // 0..63
  const int c0 = g * 128 + lane * 2;
  const int head = g >> 1;
  __shared__ int s_src[64];
  __shared__ float s_al[64];
  const float idn = 1.f / (den[n * 4 + head] + 1e-16f);
  const float* ewh = ewc + (size_t)head * ETOT;
  float ax = 0.f, ay = 0.f;
  const int beg = rowptr[n], end = rowptr[n + 1];
  for (int base = beg; base < end; base += 64) {
    const int cnt = min(64, end - base);
    __syncthreads();
    if (lane < cnt) {
      s_src[lane] = csr_src[base + lane];
      s_al[lane] = ewh[base + lane];
    }
    __syncthreads();
    int j = 0;
    const int nfull = cnt & ~7;
    for (; j < nfull; j += 8) {
      float w[8];
      half2v v[8];
#pragma unroll
      for (int u = 0; u < 8; ++u) {
        w[u] = s_al[j + u];
        v[u] = *(const half2v*)(h + (size_t)s_src[j + u] * C1 + c0);
      }
#pragma unroll
      for (int u = 0; u < 8; ++u) {
        ax += (float)v[u][0] * w[u];
        ay += (float)v[u][1] * w[u];
      }
    }
    for (; j < cnt; ++j) {
      const float w0 = s_al[j];
      const half2v v = *(const half2v*)(h + (size_t)s_src[j] * C1 + c0);
      ax += (float)v[0] * w0;
      ay += (float)v[1] * w0;
    }
  }
  float r0 = ax * idn * Af[c0] + Bf[c0];
  float r1 = ay * idn * Af[c0 + 1] + Bf[c0 + 1];
  r0 = r0 > 0.f ? r0 : expm1f(r0);  // ELU
  r1 = r1 > 0.f ? r1 : expm1f(r1);
  half2v ov;
  ov[0] = (_Float16)r0;
  ov[1] = (_Float16)r1;
  *(half2v*)(outh + (size_t)n * C1 + c0) = ov;
}

// ---------------------------------------------------------------------------
// HH=1 aggregation (layer 3): 64 thr, half4, ELU, fp16 out (feeds fc1 MFMA).
// ---------------------------------------------------------------------------
__global__ __launch_bounds__(64) void k_agg1(
    const _Float16* __restrict__ h, const int* __restrict__ rowptr,
    const int* __restrict__ csr_src, const float* __restrict__ ewc,
    const float* __restrict__ den, const float* __restrict__ bias,
    _Float16* __restrict__ outh) {
  const int n = blockIdx.x;
  const int tid = threadIdx.x;
  const int c0 = tid * 4;
  __shared__ int s_src[64];
  __shared__ float s_al[64];
  const float idn = 1.f / (den[n] + 1e-16f);
  float acc[4] = {};
  const int beg = rowptr[n], end = rowptr[n + 1];
  for (int base = beg; base < end; base += 64) {
    const int cnt = min(64, end - base);
    __syncthreads();
    if (tid < cnt) {
      s_src[tid] = csr_src[base + tid];
      s_al[tid] = ewc[base + tid];
    }
    __syncthreads();
    int j = 0;
    const int nfull = cnt & ~7;
    for (; j < nfull; j += 8) {
      float w[8];
      half4 v[8];
#pragma unroll
      for (int u = 0; u < 8; ++u) {
        w[u] = s_al[j + u];
        v[u] = *(const half4*)(h + (size_t)s_src[j + u] * DH + c0);
      }
#pragma unroll
      for (int u = 0; u < 8; ++u)
#pragma unroll
        for (int i = 0; i < 4; ++i) acc[i] += (float)v[u][i] * w[u];
    }
    for (; j < cnt; ++j) {
      const float w0 = s_al[j];
      const half4 v = *(const half4*)(h + (size_t)s_src[j] * DH + c0);
#pragma unroll
      for (int i = 0; i < 4; ++i) acc[i] += (float)v[i] * w0;
    }
  }
  half4 ov;
#pragma unroll
  for (int i = 0; i < 4; i++) {
    const int c = c0 + i;
    float val = acc[i] * idn + bias[c];
    val = val > 0.f ? val : expm1f(val);  // ELU
    ov[i] = (_Float16)val;
  }
  *(half4*)(outh + (size_t)n * DH + c0) = ov;
}

// ---------------------------------------------------------------------------
extern "C" void kernel_launch(void* const* d_in, const int* in_sizes, int n_in,
                              void* d_out, int out_size, void* d_ws,
                              size_t ws_size, hipStream_t stream) {
  const float* x    = (const float*)d_in[0];
  const int*   ei   = (const int*)d_in[1];
  const float* W1   = (const float*)d_in[2];
  const float* a1s  = (const float*)d_in[3];
  const float* a1d  = (const float*)d_in[4];
  const float* b1   = (const float*)d_in[5];
  const float* W2   = (const float*)d_in[6];
  const float* a2s  = (const float*)d_in[7];
  const float* a2d  = (const float*)d_in[8];
  const float* b2   = (const float*)d_in[9];
  const float* W3   = (const float*)d_in[10];
  const float* a3s  = (const float*)d_in[11];
  const float* a3d  = (const float*)d_in[12];
  const float* b3   = (const float*)d_in[13];
  const float* g1   = (const float*)d_in[14];
  const float* be1  = (const float*)d_in[15];
  const float* m1   = (const float*)d_in[16];
  const float* v1   = (const float*)d_in[17];
  const float* g2   = (const float*)d_in[18];
  const float* be2  = (const float*)d_in[19];
  const float* m2   = (const float*)d_in[20];
  const float* v2   = (const float*)d_in[21];
  const float* fc1W = (const float*)d_in[22];
  const float* fc1b = (const float*)d_in[23];
  const float* fc2W = (const float*)d_in[24];
  const float* fc2b = (const float*)d_in[25];
  float* out = (float*)d_out;

  char* p = (char*)d_ws;
  auto alloc = [&](size_t bytes) -> void* {
    void* r = (void*)p;
    p += (bytes + 255) & ~(size_t)255;
    return r;
  };
  _Float16* hA     = (_Float16*)alloc((size_t)M_PAD * C1 * 2);  // GEMM input (holds xh first)
  _Float16* hG     = (_Float16*)alloc((size_t)M_PAD * C1 * 2);  // GEMM output
  _Float16* wh     = (_Float16*)alloc((size_t)C1 * C1 * 2);
  _Float16* y16    = (_Float16*)alloc((size_t)M_PAD * DH * 2);  // agg3 out (fp16) -> fc1 A
  float*    buf0   = (float*)alloc((size_t)N_NODES * 128 * 4);  // fc1 out
  float*    as_    = (float*)alloc((size_t)N_NODES * HEADS * 4);
  float*    ad_    = (float*)alloc((size_t)N_NODES * HEADS * 4);
  float*    den    = (float*)alloc((size_t)N_NODES * HEADS * 4);
  float*    ewc    = (float*)alloc((size_t)ETOT * HEADS * 4);   // [head][ETOT]
  float*    Afold  = (float*)alloc((size_t)C1 * 4);
  float*    Bfold  = (float*)alloc((size_t)C1 * 4);
  int*      rowptr = (int*)alloc((size_t)(N_NODES + 1) * 4);
  int*      cnt    = (int*)alloc((size_t)N_NODES * 4);
  int*      csrS   = (int*)alloc((size_t)ETOT * 4);
  int*      einv   = (int*)alloc((size_t)ETOT * 4);

  const int eb = (ETOT + 255) / 256;
  _Float16* xh = hA;  // alias: [M_PAD][K1PAD]

  // ---- CSR build (graph identical for all three layers) ----
  hipMemsetAsync(cnt, 0, (size_t)N_NODES * 4, stream);
  k_count<<<eb, 256, 0, stream>>>(ei, cnt);
  k_scan<<<1, 256, 0, stream>>>(cnt, rowptr);
  hipMemsetAsync(cnt, 0, (size_t)N_NODES * 4, stream);
  k_fill<<<eb, 256, 0, stream>>>(ei, rowptr, cnt, csrS, einv);

  // ---- Layer 1: GATConv(300 -> 4x256) + BN1 + ELU ----
  k_cvt<<<(N_NODES * (K1PAD / 2) + 255) / 256, 256, 0, stream>>>(
      x, xh, N_NODES, F_INDIM, K1PAD);
  k_cvt<<<(C1 * (K1PAD / 2) + 255) / 256, 256, 0, stream>>>(
      W1, wh, C1, F_INDIM, K1PAD);
  k_mfma_gemm<1, 0><<<dim3(C1 / 128, M_PAD / 128), 256, 0, stream>>>(
      xh, wh, nullptr, nullptr, hG, N_NODES, C1, K1PAD);
  k_alpha<4><<<N_NODES, 256, 0, stream>>>(hG, a1s, a1d, as_, ad_);
  hipMemsetAsync(den, 0, (size_t)N_NODES * HEADS * 4, stream);
  k_edge<4><<<eb, 256, 0, stream>>>(ei, einv, ewc, den, as_, ad_);
  k_bnp<<<(C1 + 255) / 256, 256, 0, stream>>>(b1, g1, be1, m1, v1,
                                              Afold, Bfold, C1);
  k_agg4s<<<N_NODES * 8, 64, 0, stream>>>(hG, rowptr, csrS, ewc, den,
                                          Afold, Bfold, hA);

  // ---- Layer 2: GATConv(1024 -> 4x256) + BN2 + ELU ----
  k_cvt<<<(C1 * (C1 / 2) + 255) / 256, 256, 0, stream>>>(W2, wh, C1, C1, C1);
  k_mfma_gemm<1, 0><<<dim3(C1 / 128, M_PAD / 128), 256, 0, stream>>>(
      hA, wh, nullptr, nullptr, hG, N_NODES, C1, C1);
  k_alpha<4><<<N_NODES, 256, 0, stream>>>(hG, a2s, a2d, as_, ad_);
  hipMemsetAsync(den, 0, (size_t)N_NODES * HEADS * 4, stream);
  k_edge<4><<<eb, 256, 0, stream>>>(ei, einv, ewc, den, as_, ad_);
  k_bnp<<<(C1 + 255) / 256, 256, 0, stream>>>(b2, g2, be2, m2, v2,
                                              Afold, Bfold, C1);
  k_agg4s<<<N_NODES * 8, 64, 0, stream>>>(hG, rowptr, csrS, ewc, den,
                                          Afold, Bfold, hA);

  // ---- Layer 3: GATConv(1024 -> 256, heads=1) + ELU ----
  k_cvt<<<(DH * (C1 / 2) + 255) / 256, 256, 0, stream>>>(W3, wh, DH, C1, C1);
  k_mfma_gemm<1, 0><<<dim3(DH / 128, M_PAD / 128), 256, 0, stream>>>(
      hA, wh, nullptr, nullptr, hG, N_NODES, DH, C1);
  k_alpha<1><<<N_NODES, 64, 0, stream>>>(hG, a3s, a3d, as_, ad_);
  hipMemsetAsync(den, 0, (size_t)N_NODES * 4, stream);
  k_edge<1><<<eb, 256, 0, stream>>>(ei, einv, ewc, den, as_, ad_);
  k_agg1<<<N_NODES, 64, 0, stream>>>(hG, rowptr, csrS, ewc, den, b3, y16);

  // ---- MLP head: fc1 on MFMA (bias+ReLU fused), fc2 epilogue ----
  k_cvt<<<(128 * (DH / 2) + 255) / 256, 256, 0, stream>>>(fc1W, wh, 128, DH, DH);
  k_mfma_gemm<0, 1><<<dim3(1, M_PAD / 128), 256, 0, stream>>>(
      y16, wh, fc1b, buf0, nullptr, N_NODES, 128, DH);
  k_fc2<<<N_NODES / 8, 256, 0, stream>>>(buf0, fc2W, fc2b, out);
}

// Round 13
// 444.834 us; speedup vs baseline: 1.4092x; 1.0542x over previous
//
#include <hip/hip_runtime.h>
#include <cstdint>
#include <cstddef>

#define N_NODES 10000
#define M_PAD   10112            // 79 * 128
#define N_EDGES 160000
#define ETOT    (N_EDGES + N_NODES)   // with self-loops
#define F_INDIM 300
#define K1PAD   320              // F_INDIM padded to mult of 32
#define HEADS   4
#define DH      256
#define C1      (HEADS * DH)     // 1024
#define NCLS    6
#define BN_EPS  1e-5f

typedef _Float16 half8 __attribute__((ext_vector_type(8)));
typedef _Float16 half4 __attribute__((ext_vector_type(4)));
typedef _Float16 half2v __attribute__((ext_vector_type(2)));
typedef float f32x4 __attribute__((ext_vector_type(4)));

__device__ __forceinline__ void gld_lds16(const void* g, void* s) {
  __builtin_amdgcn_global_load_lds(
      (const __attribute__((address_space(1))) void*)g,
      (__attribute__((address_space(3))) void*)s, 16, 0, 0);
}

// ---------------------------------------------------------------------------
// fp16 MFMA GEMM: C[M,Nn] = A[M,K]fp16 @ B[Nn,K]fp16^T (NT), fp16 out.
// 128x128 tile, BK=32, 256 threads = 4 waves (2x2), 4x4 16x16x32 frags/wave.
// ---------------------------------------------------------------------------
__global__ __launch_bounds__(256) void k_mfma_gemm(
    const _Float16* __restrict__ A, const _Float16* __restrict__ B,
    _Float16* __restrict__ Ch, int M, int Nn, int K) {
  __shared__ __align__(16) _Float16 sA[128 * 32];
  __shared__ __align__(16) _Float16 sB[128 * 32];
  const int tid = threadIdx.x;
  const int lane = tid & 63, w = tid >> 6;
  const int wm = w >> 1, wn = w & 1;
  const int row0 = blockIdx.y * 128, col0 = blockIdx.x * 128;

  const int r_loc = lane >> 2;       // 0..15
  const int j8 = (lane & 3) * 8;     // half offset within BK=32
  const _Float16* gA = A + (size_t)(row0 + w * 32 + r_loc) * K + j8;
  const _Float16* gB = B + (size_t)(col0 + w * 32 + r_loc) * K + j8;
  _Float16* sAw = sA + (w * 32) * 32;
  _Float16* sBw = sB + (w * 32) * 32;

  const int fr = lane & 15, kb = lane >> 4;
  const _Float16* pA = sA + ((size_t)(wm * 64 + fr) * 32 + kb * 8);
  const _Float16* pB = sB + ((size_t)(wn * 64 + fr) * 32 + kb * 8);

  f32x4 acc[4][4] = {};
  const int KT = K / 32;

  {
    gld_lds16(gA, sAw);
    gld_lds16(gA + (size_t)16 * K, sAw + 16 * 32);
    gld_lds16(gB, sBw);
    gld_lds16(gB + (size_t)16 * K, sBw + 16 * 32);
  }
  for (int kt = 0; kt < KT; ++kt) {
    __syncthreads();
    half8 af[4], bf[4];
#pragma unroll
    for (int i = 0; i < 4; ++i) af[i] = *(const half8*)(pA + i * 16 * 32);
#pragma unroll
    for (int j = 0; j < 4; ++j) bf[j] = *(const half8*)(pB + j * 16 * 32);
    __syncthreads();
    if (kt + 1 < KT) {
      const _Float16* ga = gA + (size_t)(kt + 1) * 32;
      const _Float16* gb = gB + (size_t)(kt + 1) * 32;
      gld_lds16(ga, sAw);
      gld_lds16(ga + (size_t)16 * K, sAw + 16 * 32);
      gld_lds16(gb, sBw);
      gld_lds16(gb + (size_t)16 * K, sBw + 16 * 32);
    }
#pragma unroll
    for (int i = 0; i < 4; ++i)
#pragma unroll
      for (int j = 0; j < 4; ++j)
        acc[i][j] =
            __builtin_amdgcn_mfma_f32_16x16x32_f16(af[i], bf[j], acc[i][j], 0, 0, 0);
  }

  // C/D layout: col = lane&15, row = (lane>>4)*4 + reg
  const int orow = row0 + wm * 64 + kb * 4;
  const int ocol = col0 + wn * 64 + fr;
#pragma unroll
  for (int i = 0; i < 4; ++i) {
#pragma unroll
    for (int r = 0; r < 4; ++r) {
      const int rr = orow + i * 16 + r;
      if (rr >= M) continue;
#pragma unroll
      for (int j = 0; j < 4; ++j)
        Ch[(size_t)rr * Nn + ocol + j * 16] = (_Float16)acc[i][j][r];
    }
  }
}

// ---------------------------------------------------------------------------
// Fused MLP head (round 13): fc1 MFMA GEMM (y16[10112,256] @ fc1W[128,256]^T,
// bias+ReLU) -> LDS -> in-block fc2 (6 cols). Grid = 79 x 128-row blocks;
// each block owns its nodes' ENTIRE fc1 row => no global round trip.
// ---------------------------------------------------------------------------
__global__ __launch_bounds__(256) void k_fc12(
    const _Float16* __restrict__ A, const _Float16* __restrict__ B,
    const float* __restrict__ b1f, const float* __restrict__ W2,
    const float* __restrict__ b2f, float* __restrict__ out) {
  __shared__ __align__(16) _Float16 sA[128 * 32];
  __shared__ __align__(16) _Float16 sB[128 * 32];
  __shared__ _Float16 sy[128][133];  // pad 133: 133*2B stride decorrelates banks
  const int tid = threadIdx.x;
  const int lane = tid & 63, w = tid >> 6;
  const int wm = w >> 1, wn = w & 1;
  const int row0 = blockIdx.x * 128;
  const int K = DH;  // 256

  const int r_loc = lane >> 2;
  const int j8 = (lane & 3) * 8;
  const _Float16* gA = A + (size_t)(row0 + w * 32 + r_loc) * K + j8;
  const _Float16* gB = B + (size_t)(w * 32 + r_loc) * K + j8;  // 128 W-rows
  _Float16* sAw = sA + (w * 32) * 32;
  _Float16* sBw = sB + (w * 32) * 32;

  const int fr = lane & 15, kb = lane >> 4;
  const _Float16* pA = sA + ((size_t)(wm * 64 + fr) * 32 + kb * 8);
  const _Float16* pB = sB + ((size_t)(wn * 64 + fr) * 32 + kb * 8);

  f32x4 acc[4][4] = {};
  const int KT = K / 32;  // 8
  {
    gld_lds16(gA, sAw);
    gld_lds16(gA + (size_t)16 * K, sAw + 16 * 32);
    gld_lds16(gB, sBw);
    gld_lds16(gB + (size_t)16 * K, sBw + 16 * 32);
  }
  for (int kt = 0; kt < KT; ++kt) {
    __syncthreads();
    half8 af[4], bf[4];
#pragma unroll
    for (int i = 0; i < 4; ++i) af[i] = *(const half8*)(pA + i * 16 * 32);
#pragma unroll
    for (int j = 0; j < 4; ++j) bf[j] = *(const half8*)(pB + j * 16 * 32);
    __syncthreads();
    if (kt + 1 < KT) {
      const _Float16* ga = gA + (size_t)(kt + 1) * 32;
      const _Float16* gb = gB + (size_t)(kt + 1) * 32;
      gld_lds16(ga, sAw);
      gld_lds16(ga + (size_t)16 * K, sAw + 16 * 32);
      gld_lds16(gb, sBw);
      gld_lds16(gb + (size_t)16 * K, sBw + 16 * 32);
    }
#pragma unroll
    for (int i = 0; i < 4; ++i)
#pragma unroll
      for (int j = 0; j < 4; ++j)
        acc[i][j] =
            __builtin_amdgcn_mfma_f32_16x16x32_f16(af[i], bf[j], acc[i][j], 0, 0, 0);
  }
  // relu(fc1) -> LDS (all 128x128, padding rows included; guarded at store)
  const int lrow = wm * 64 + kb * 4;
  const int lcol = wn * 64 + fr;
#pragma unroll
  for (int i = 0; i < 4; ++i)
#pragma unroll
    for (int r = 0; r < 4; ++r)
#pragma unroll
      for (int j = 0; j < 4; ++j) {
        float v = acc[i][j][r] + b1f[lcol + j * 16];
        sy[lrow + i * 16 + r][lcol + j * 16] = (_Float16)(v > 0.f ? v : 0.f);
      }
  __syncthreads();
  // fc2: 768 outputs = 256 threads x 3
#pragma unroll
  for (int q = 0; q < 3; ++q) {
    const int idx = tid * 3 + q;
    const int n = idx / NCLS, c = idx % NCLS;
    if (row0 + n < N_NODES) {
      float s = b2f[c];
      const float* w2 = W2 + c * 128;
#pragma unroll 8
      for (int k = 0; k < 128; ++k) s += (float)sy[n][k] * w2[k];
      out[(size_t)(row0 + n) * NCLS + c] = s;
    }
  }
}

// ---------------------------------------------------------------------------
// Mega-cvt: all fp32->fp16 conversions in ONE launch (segments compile-time).
// ---------------------------------------------------------------------------
__device__ __forceinline__ void cvt_pair(const float* __restrict__ in,
                                         _Float16* __restrict__ out, int i,
                                         int K, int Kp) {
  const int kp2 = Kp >> 1;
  const int r = i / kp2, c2 = (i % kp2) * 2;
  const float vx = (c2 < K) ? in[(size_t)r * K + c2] : 0.f;
  const float vy = (c2 + 1 < K) ? in[(size_t)r * K + c2 + 1] : 0.f;
  out[(size_t)r * Kp + c2] = (_Float16)vx;
  out[(size_t)r * Kp + c2 + 1] = (_Float16)vy;
}

#define CV_S0 (N_NODES * (K1PAD / 2))   // x:    1,600,000
#define CV_S1 (C1 * (K1PAD / 2))        // W1:     163,840
#define CV_S2 (C1 * (C1 / 2))           // W2:     524,288
#define CV_S3 (DH * (C1 / 2))           // W3:     131,072
#define CV_S4 (128 * (DH / 2))          // fc1W:    16,384
#define CV_TOT (CV_S0 + CV_S1 + CV_S2 + CV_S3 + CV_S4)

__global__ __launch_bounds__(256) void k_cvt_all(
    const float* __restrict__ x, const float* __restrict__ W1,
    const float* __restrict__ W2, const float* __restrict__ W3,
    const float* __restrict__ fcW, _Float16* __restrict__ xh,
    _Float16* __restrict__ w1h, _Float16* __restrict__ w2h,
    _Float16* __restrict__ w3h, _Float16* __restrict__ fwh) {
  int i = blockIdx.x * 256 + threadIdx.x;
  if (i < CV_S0) { cvt_pair(x, xh, i, F_INDIM, K1PAD); return; }
  i -= CV_S0;
  if (i < CV_S1) { cvt_pair(W1, w1h, i, F_INDIM, K1PAD); return; }
  i -= CV_S1;
  if (i < CV_S2) { cvt_pair(W2, w2h, i, C1, C1); return; }
  i -= CV_S2;
  if (i < CV_S3) { cvt_pair(W3, w3h, i, C1, C1); return; }
  i -= CV_S3;
  if (i < CV_S4) { cvt_pair(fcW, fwh, i, DH, DH); return; }
}

// ---------------------------------------------------------------------------
// Fold bias+BN for BOTH layers: A/B[0..1024) = layer1, [1024..2048) = layer2.
// ---------------------------------------------------------------------------
__global__ __launch_bounds__(256) void k_bnp2(
    const float* __restrict__ b1, const float* __restrict__ g1,
    const float* __restrict__ be1, const float* __restrict__ m1,
    const float* __restrict__ v1, const float* __restrict__ b2,
    const float* __restrict__ g2, const float* __restrict__ be2,
    const float* __restrict__ m2, const float* __restrict__ v2,
    float* __restrict__ A, float* __restrict__ B) {
  const int c = blockIdx.x * 256 + threadIdx.x;
  if (c >= 2 * C1) return;
  if (c < C1) {
    const float rs = rsqrtf(v1[c] + BN_EPS) * g1[c];
    A[c] = rs;
    B[c] = (b1[c] - m1[c]) * rs + be1[c];
  } else {
    const int d = c - C1;
    const float rs = rsqrtf(v2[d] + BN_EPS) * g2[d];
    A[c] = rs;
    B[c] = (b2[d] - m2[d]) * rs + be2[d];
  }
}

// ---------------------------------------------------------------------------
// alpha_s[n,h] = <h[n,h,:], a_src[h,:]> from fp16 h. Block = HH*64.
// ---------------------------------------------------------------------------
template <int HH>
__global__ __launch_bounds__(HH * 64) void k_alpha(
    const _Float16* __restrict__ h, const float* __restrict__ a_src,
    const float* __restrict__ a_dst, float* __restrict__ as_,
    float* __restrict__ ad_) {
  const int n = blockIdx.x;
  const int tid = threadIdx.x;
  const int head = tid >> 6;
  const int lane = tid & 63;
  const half4 hv = *(const half4*)(h + (size_t)n * HH * DH + head * DH + lane * 4);
  const float4 sv = *(reinterpret_cast<const float4*>(a_src + head * DH) + lane);
  const float4 dv = *(reinterpret_cast<const float4*>(a_dst + head * DH) + lane);
  const float h0 = (float)hv[0], h1 = (float)hv[1], h2 = (float)hv[2],
              h3 = (float)hv[3];
  float s1 = h0 * sv.x + h1 * sv.y + h2 * sv.z + h3 * sv.w;
  float s2 = h0 * dv.x + h1 * dv.y + h2 * dv.z + h3 * dv.w;
#pragma unroll
  for (int off = 32; off > 0; off >>= 1) {
    s1 += __shfl_down(s1, off);
    s2 += __shfl_down(s2, off);
  }
  if (lane == 0) {
    as_[n * HH + head] = s1;
    ad_[n * HH + head] = s2;
  }
}

// ---------------------------------------------------------------------------
// Per edge: all heads. w = exp(leaky_relu(as[src]+ad[dst])).
// ewc layout: PLANES [head][ETOT] in CSR slot order.
// ---------------------------------------------------------------------------
template <int HH>
__global__ __launch_bounds__(256) void k_edge(
    const int* __restrict__ ei, const int* __restrict__ einv,
    float* __restrict__ ewc, float* __restrict__ den,
    const float* __restrict__ as_, const float* __restrict__ ad_) {
  const int e = blockIdx.x * 256 + threadIdx.x;
  if (e >= ETOT) return;
  int s, t;
  if (e < N_EDGES) { s = ei[e]; t = ei[N_EDGES + e]; }
  else             { s = t = e - N_EDGES; }
  const int pos = einv[e];
#pragma unroll
  for (int hh = 0; hh < HH; ++hh) {
    float x = as_[s * HH + hh] + ad_[t * HH + hh];
    x = x > 0.f ? x : 0.2f * x;
    const float w = expf(x);
    ewc[(size_t)hh * ETOT + pos] = w;
    atomicAdd(&den[t * HH + hh], w);
  }
}

// ---------------------------------------------------------------------------
// CSR build (cnt1 for count, cnt2 for fill -> both zeroed by the one memset)
// ---------------------------------------------------------------------------
__global__ __launch_bounds__(256) void k_count(const int* __restrict__ ei,
                                               int* __restrict__ cnt) {
  const int e = blockIdx.x * 256 + threadIdx.x;
  if (e >= ETOT) return;
  const int t = (e < N_EDGES) ? ei[N_EDGES + e] : (e - N_EDGES);
  atomicAdd(&cnt[t], 1);
}

__global__ __launch_bounds__(256) void k_scan(const int* __restrict__ cnt,
                                              int* __restrict__ rowptr) {
  __shared__ int part[256];
  const int tid = threadIdx.x;
  const int chunk = (N_NODES + 255) / 256;  // 40
  const int b = tid * chunk;
  int sum = 0;
  for (int i = 0; i < chunk; i++) {
    const int idx = b + i;
    if (idx < N_NODES) sum += cnt[idx];
  }
  part[tid] = sum;
  __syncthreads();
  for (int off = 1; off < 256; off <<= 1) {
    int t2 = (tid >= off) ? part[tid - off] : 0;
    __syncthreads();
    part[tid] += t2;
    __syncthreads();
  }
  int run = part[tid] - sum;
  for (int i = 0; i < chunk; i++) {
    const int idx = b + i;
    if (idx < N_NODES) {
      rowptr[idx] = run;
      run += cnt[idx];
    }
  }
  if (tid == 255) rowptr[N_NODES] = part[255];
}

__global__ __launch_bounds__(256) void k_fill(
    const int* __restrict__ ei, const int* __restrict__ rowptr,
    int* __restrict__ fill, int* __restrict__ csr_src,
    int* __restrict__ einv) {
  const int e = blockIdx.x * 256 + threadIdx.x;
  if (e >= ETOT) return;
  int s, t;
  if (e < N_EDGES) { s = ei[e]; t = ei[N_EDGES + e]; }
  else             { s = t = e - N_EDGES; }
  const int pos = rowptr[t] + atomicAdd(&fill[t], 1);
  csr_src[pos] = s;
  einv[e] = pos;
}

// ---------------------------------------------------------------------------
// HH=4 aggregation, XCD-sliced (verified R11): grid = N*8, block = 64.
// Block b: node b>>3, column group b&7 -> 2.56MB slice fits one XCD's L2.
// ---------------------------------------------------------------------------
__global__ __launch_bounds__(64) void k_agg4s(
    const _Float16* __restrict__ h, const int* __restrict__ rowptr,
    const int* __restrict__ csr_src, const float* __restrict__ ewc,
    const float* __restrict__ den, const float* __restrict__ Af,
    const float* __restrict__ Bf, _Float16* __restrict__ outh) {
  const int b = blockIdx.x;
  const int g = b & 7;            // column group -> XCD
  const int n = b >> 3;           // node
  const int lane = threadIdx.x;   // 0..63
  const int c0 = g * 128 + lane * 2;
  const int head = g >> 1;
  __shared__ int s_src[64];
  __shared__ float s_al[64];
  const float idn = 1.f / (den[n * 4 + head] + 1e-16f);
  const float* ewh = ewc + (size_t)head * ETOT;
  float ax = 0.f, ay = 0.f;
  const int beg = rowptr[n], end = rowptr[n + 1];
  for (int base = beg; base < end; base += 64) {
    const int cnt = min(64, end - base);
    __syncthreads();
    if (lane < cnt) {
      s_src[lane] = csr_src[base + lane];
      s_al[lane] = ewh[base + lane];
    }
    __syncthreads();
    int j = 0;
    const int nfull = cnt & ~7;
    for (; j < nfull; j += 8) {
      float w[8];
      half2v v[8];
#pragma unroll
      for (int u = 0; u < 8; ++u) {
        w[u] = s_al[j + u];
        v[u] = *(const half2v*)(h + (size_t)s_src[j + u] * C1 + c0);
      }
#pragma unroll
      for (int u = 0; u < 8; ++u) {
        ax += (float)v[u][0] * w[u];
        ay += (float)v[u][1] * w[u];
      }
    }
    for (; j < cnt; ++j) {
      const float w0 = s_al[j];
      const half2v v = *(const half2v*)(h + (size_t)s_src[j] * C1 + c0);
      ax += (float)v[0] * w0;
      ay += (float)v[1] * w0;
    }
  }
  float r0 = ax * idn * Af[c0] + Bf[c0];
  float r1 = ay * idn * Af[c0 + 1] + Bf[c0 + 1];
  r0 = r0 > 0.f ? r0 : expm1f(r0);  // ELU
  r1 = r1 > 0.f ? r1 : expm1f(r1);
  half2v ov;
  ov[0] = (_Float16)r0;
  ov[1] = (_Float16)r1;
  *(half2v*)(outh + (size_t)n * C1 + c0) = ov;
}

// ---------------------------------------------------------------------------
// HH=1 aggregation (layer 3): 64 thr, half4, ELU, fp16 out (feeds fc12).
// ---------------------------------------------------------------------------
__global__ __launch_bounds__(64) void k_agg1(
    const _Float16* __restrict__ h, const int* __restrict__ rowptr,
    const int* __restrict__ csr_src, const float* __restrict__ ewc,
    const float* __restrict__ den, const float* __restrict__ bias,
    _Float16* __restrict__ outh) {
  const int n = blockIdx.x;
  const int tid = threadIdx.x;
  const int c0 = tid * 4;
  __shared__ int s_src[64];
  __shared__ float s_al[64];
  const float idn = 1.f / (den[n] + 1e-16f);
  float acc[4] = {};
  const int beg = rowptr[n], end = rowptr[n + 1];
  for (int base = beg; base < end; base += 64) {
    const int cnt = min(64, end - base);
    __syncthreads();
    if (tid < cnt) {
      s_src[tid] = csr_src[base + tid];
      s_al[tid] = ewc[base + tid];
    }
    __syncthreads();
    int j = 0;
    const int nfull = cnt & ~7;
    for (; j < nfull; j += 8) {
      float w[8];
      half4 v[8];
#pragma unroll
      for (int u = 0; u < 8; ++u) {
        w[u] = s_al[j + u];
        v[u] = *(const half4*)(h + (size_t)s_src[j + u] * DH + c0);
      }
#pragma unroll
      for (int u = 0; u < 8; ++u)
#pragma unroll
        for (int i = 0; i < 4; ++i) acc[i] += (float)v[u][i] * w[u];
    }
    for (; j < cnt; ++j) {
      const float w0 = s_al[j];
      const half4 v = *(const half4*)(h + (size_t)s_src[j] * DH + c0);
#pragma unroll
      for (int i = 0; i < 4; ++i) acc[i] += (float)v[i] * w0;
    }
  }
  half4 ov;
#pragma unroll
  for (int i = 0; i < 4; i++) {
    const int c = c0 + i;
    float val = acc[i] * idn + bias[c];
    val = val > 0.f ? val : expm1f(val);  // ELU
    ov[i] = (_Float16)val;
  }
  *(half4*)(outh + (size_t)n * DH + c0) = ov;
}

// ---------------------------------------------------------------------------
extern "C" void kernel_launch(void* const* d_in, const int* in_sizes, int n_in,
                              void* d_out, int out_size, void* d_ws,
                              size_t ws_size, hipStream_t stream) {
  const float* x    = (const float*)d_in[0];
  const int*   ei   = (const int*)d_in[1];
  const float* W1   = (const float*)d_in[2];
  const float* a1s  = (const float*)d_in[3];
  const float* a1d  = (const float*)d_in[4];
  const float* b1   = (const float*)d_in[5];
  const float* W2   = (const float*)d_in[6];
  const float* a2s  = (const float*)d_in[7];
  const float* a2d  = (const float*)d_in[8];
  const float* b2   = (const float*)d_in[9];
  const float* W3   = (const float*)d_in[10];
  const float* a3s  = (const float*)d_in[11];
  const float* a3d  = (const float*)d_in[12];
  const float* b3   = (const float*)d_in[13];
  const float* g1   = (const float*)d_in[14];
  const float* be1  = (const float*)d_in[15];
  const float* m1   = (const float*)d_in[16];
  const float* v1   = (const float*)d_in[17];
  const float* g2   = (const float*)d_in[18];
  const float* be2  = (const float*)d_in[19];
  const float* m2   = (const float*)d_in[20];
  const float* v2   = (const float*)d_in[21];
  const float* fc1W = (const float*)d_in[22];
  const float* fc1b = (const float*)d_in[23];
  const float* fc2W = (const float*)d_in[24];
  const float* fc2b = (const float*)d_in[25];
  float* out = (float*)d_out;

  char* p = (char*)d_ws;
  auto alloc = [&](size_t bytes) -> void* {
    void* r = (void*)p;
    p += (bytes + 255) & ~(size_t)255;
    return r;
  };
  _Float16* hA     = (_Float16*)alloc((size_t)M_PAD * C1 * 2);  // GEMM in (holds xh)
  _Float16* hG     = (_Float16*)alloc((size_t)M_PAD * C1 * 2);  // GEMM out
  _Float16* w1h    = (_Float16*)alloc((size_t)C1 * K1PAD * 2);
  _Float16* w2h    = (_Float16*)alloc((size_t)C1 * C1 * 2);
  _Float16* w3h    = (_Float16*)alloc((size_t)DH * C1 * 2);
  _Float16* fwh    = (_Float16*)alloc((size_t)128 * DH * 2);
  _Float16* y16    = (_Float16*)alloc((size_t)M_PAD * DH * 2);  // agg3 out
  float*    as_    = (float*)alloc((size_t)N_NODES * HEADS * 4);
  float*    ad_    = (float*)alloc((size_t)N_NODES * HEADS * 4);
  float*    ewc    = (float*)alloc((size_t)ETOT * HEADS * 4);   // [head][ETOT]
  float*    Afold  = (float*)alloc((size_t)2 * C1 * 4);
  float*    Bfold  = (float*)alloc((size_t)2 * C1 * 4);
  int*      rowptr = (int*)alloc((size_t)(N_NODES + 1) * 4);
  int*      csrS   = (int*)alloc((size_t)ETOT * 4);
  int*      einv   = (int*)alloc((size_t)ETOT * 4);
  // single zero-block: cnt1[N] cnt2[N] denA[4N] denB[4N] denC[N]
  const size_t ZN = (size_t)N_NODES * (1 + 1 + 4 + 4 + 1) * 4;  // 440000 B
  char*     zbuf   = (char*)alloc(ZN);
  int*      cnt1   = (int*)zbuf;
  int*      cnt2   = cnt1 + N_NODES;
  float*    denA   = (float*)(cnt2 + N_NODES);
  float*    denB   = denA + (size_t)N_NODES * 4;
  float*    denC   = denB + (size_t)N_NODES * 4;

  const int eb = (ETOT + 255) / 256;
  _Float16* xh = hA;  // alias: [M_PAD][K1PAD], gemm1 reads before agg1 writes

  // ---- one memset for all counters + denominators ----
  hipMemsetAsync(zbuf, 0, ZN, stream);
  // ---- CSR build ----
  k_count<<<eb, 256, 0, stream>>>(ei, cnt1);
  k_scan<<<1, 256, 0, stream>>>(cnt1, rowptr);
  k_fill<<<eb, 256, 0, stream>>>(ei, rowptr, cnt2, csrS, einv);
  // ---- all conversions + BN folds (input-only deps) ----
  k_cvt_all<<<(CV_TOT + 255) / 256, 256, 0, stream>>>(
      x, W1, W2, W3, fc1W, xh, w1h, w2h, w3h, fwh);
  k_bnp2<<<(2 * C1 + 255) / 256, 256, 0, stream>>>(
      b1, g1, be1, m1, v1, b2, g2, be2, m2, v2, Afold, Bfold);

  // ---- Layer 1: GATConv(300 -> 4x256) + BN1 + ELU ----
  k_mfma_gemm<<<dim3(C1 / 128, M_PAD / 128), 256, 0, stream>>>(
      xh, w1h, hG, N_NODES, C1, K1PAD);
  k_alpha<4><<<N_NODES, 256, 0, stream>>>(hG, a1s, a1d, as_, ad_);
  k_edge<4><<<eb, 256, 0, stream>>>(ei, einv, ewc, denA, as_, ad_);
  k_agg4s<<<N_NODES * 8, 64, 0, stream>>>(hG, rowptr, csrS, ewc, denA,
                                          Afold, Bfold, hA);

  // ---- Layer 2: GATConv(1024 -> 4x256) + BN2 + ELU ----
  k_mfma_gemm<<<dim3(C1 / 128, M_PAD / 128), 256, 0, stream>>>(
      hA, w2h, hG, N_NODES, C1, C1);
  k_alpha<4><<<N_NODES, 256, 0, stream>>>(hG, a2s, a2d, as_, ad_);
  k_edge<4><<<eb, 256, 0, stream>>>(ei, einv, ewc, denB, as_, ad_);
  k_agg4s<<<N_NODES * 8, 64, 0, stream>>>(hG, rowptr, csrS, ewc, denB,
                                          Afold + C1, Bfold + C1, hA);

  // ---- Layer 3: GATConv(1024 -> 256, heads=1) + ELU ----
  k_mfma_gemm<<<dim3(DH / 128, M_PAD / 128), 256, 0, stream>>>(
      hA, w3h, hG, N_NODES, DH, C1);
  k_alpha<1><<<N_NODES, 64, 0, stream>>>(hG, a3s, a3d, as_, ad_);
  k_edge<1><<<eb, 256, 0, stream>>>(ei, einv, ewc, denC, as_, ad_);
  k_agg1<<<N_NODES, 64, 0, stream>>>(hG, rowptr, csrS, ewc, denC, b3, y16);

  // ---- Fused MLP head: fc1 MFMA + in-block fc2 ----
  k_fc12<<<M_PAD / 128, 256, 0, stream>>>(y16, fwh, fc1b, fc2W, fc2b, out);
}

// Round 14
// 348.494 us; speedup vs baseline: 1.7988x; 1.2764x over previous
//
#include <hip/hip_runtime.h>
#include <cstdint>
#include <cstddef>

#define N_NODES 10000
#define M_PAD   10112            // 79 * 128
#define N_EDGES 160000
#define ETOT    (N_EDGES + N_NODES)   // with self-loops
#define F_INDIM 300
#define K1PAD   320              // F_INDIM padded to mult of 32
#define HEADS   4
#define DH      256
#define C1      (HEADS * DH)     // 1024
#define NCLS    6
#define BN_EPS  1e-5f

typedef _Float16 half8 __attribute__((ext_vector_type(8)));
typedef _Float16 half4 __attribute__((ext_vector_type(4)));
typedef _Float16 half2v __attribute__((ext_vector_type(2)));
typedef float f32x4 __attribute__((ext_vector_type(4)));

__device__ __forceinline__ void gld_lds16(const void* g, void* s) {
  __builtin_amdgcn_global_load_lds(
      (const __attribute__((address_space(1))) void*)g,
      (__attribute__((address_space(3))) void*)s, 16, 0, 0);
}

// ---------------------------------------------------------------------------
// fp16 MFMA GEMM: C[M,Nn] = A[M,K]fp16 @ B[Nn,K]fp16^T (NT), fp16 out.
// 128x128 tile, BK=32, 256 threads = 4 waves (2x2), 4x4 16x16x32 frags/wave.
// ---------------------------------------------------------------------------
__global__ __launch_bounds__(256) void k_mfma_gemm(
    const _Float16* __restrict__ A, const _Float16* __restrict__ B,
    _Float16* __restrict__ Ch, int M, int Nn, int K) {
  __shared__ __align__(16) _Float16 sA[128 * 32];
  __shared__ __align__(16) _Float16 sB[128 * 32];
  const int tid = threadIdx.x;
  const int lane = tid & 63, w = tid >> 6;
  const int wm = w >> 1, wn = w & 1;
  const int row0 = blockIdx.y * 128, col0 = blockIdx.x * 128;

  const int r_loc = lane >> 2;       // 0..15
  const int j8 = (lane & 3) * 8;     // half offset within BK=32
  const _Float16* gA = A + (size_t)(row0 + w * 32 + r_loc) * K + j8;
  const _Float16* gB = B + (size_t)(col0 + w * 32 + r_loc) * K + j8;
  _Float16* sAw = sA + (w * 32) * 32;
  _Float16* sBw = sB + (w * 32) * 32;

  const int fr = lane & 15, kb = lane >> 4;
  const _Float16* pA = sA + ((size_t)(wm * 64 + fr) * 32 + kb * 8);
  const _Float16* pB = sB + ((size_t)(wn * 64 + fr) * 32 + kb * 8);

  f32x4 acc[4][4] = {};
  const int KT = K / 32;

  {
    gld_lds16(gA, sAw);
    gld_lds16(gA + (size_t)16 * K, sAw + 16 * 32);
    gld_lds16(gB, sBw);
    gld_lds16(gB + (size_t)16 * K, sBw + 16 * 32);
  }
  for (int kt = 0; kt < KT; ++kt) {
    __syncthreads();
    half8 af[4], bf[4];
#pragma unroll
    for (int i = 0; i < 4; ++i) af[i] = *(const half8*)(pA + i * 16 * 32);
#pragma unroll
    for (int j = 0; j < 4; ++j) bf[j] = *(const half8*)(pB + j * 16 * 32);
    __syncthreads();
    if (kt + 1 < KT) {
      const _Float16* ga = gA + (size_t)(kt + 1) * 32;
      const _Float16* gb = gB + (size_t)(kt + 1) * 32;
      gld_lds16(ga, sAw);
      gld_lds16(ga + (size_t)16 * K, sAw + 16 * 32);
      gld_lds16(gb, sBw);
      gld_lds16(gb + (size_t)16 * K, sBw + 16 * 32);
    }
#pragma unroll
    for (int i = 0; i < 4; ++i)
#pragma unroll
      for (int j = 0; j < 4; ++j)
        acc[i][j] =
            __builtin_amdgcn_mfma_f32_16x16x32_f16(af[i], bf[j], acc[i][j], 0, 0, 0);
  }

  // C/D layout: col = lane&15, row = (lane>>4)*4 + reg
  const int orow = row0 + wm * 64 + kb * 4;
  const int ocol = col0 + wn * 64 + fr;
#pragma unroll
  for (int i = 0; i < 4; ++i) {
#pragma unroll
    for (int r = 0; r < 4; ++r) {
      const int rr = orow + i * 16 + r;
      if (rr >= M) continue;
#pragma unroll
      for (int j = 0; j < 4; ++j)
        Ch[(size_t)rr * Nn + ocol + j * 16] = (_Float16)acc[i][j][r];
    }
  }
}

// ---------------------------------------------------------------------------
// Fused MLP head: fc1 MFMA GEMM (bias+ReLU) -> LDS -> in-block fc2 (6 cols).
// ---------------------------------------------------------------------------
__global__ __launch_bounds__(256) void k_fc12(
    const _Float16* __restrict__ A, const _Float16* __restrict__ B,
    const float* __restrict__ b1f, const float* __restrict__ W2,
    const float* __restrict__ b2f, float* __restrict__ out) {
  __shared__ __align__(16) _Float16 sA[128 * 32];
  __shared__ __align__(16) _Float16 sB[128 * 32];
  __shared__ _Float16 sy[128][133];
  const int tid = threadIdx.x;
  const int lane = tid & 63, w = tid >> 6;
  const int wm = w >> 1, wn = w & 1;
  const int row0 = blockIdx.x * 128;
  const int K = DH;  // 256

  const int r_loc = lane >> 2;
  const int j8 = (lane & 3) * 8;
  const _Float16* gA = A + (size_t)(row0 + w * 32 + r_loc) * K + j8;
  const _Float16* gB = B + (size_t)(w * 32 + r_loc) * K + j8;
  _Float16* sAw = sA + (w * 32) * 32;
  _Float16* sBw = sB + (w * 32) * 32;

  const int fr = lane & 15, kb = lane >> 4;
  const _Float16* pA = sA + ((size_t)(wm * 64 + fr) * 32 + kb * 8);
  const _Float16* pB = sB + ((size_t)(wn * 64 + fr) * 32 + kb * 8);

  f32x4 acc[4][4] = {};
  const int KT = K / 32;  // 8
  {
    gld_lds16(gA, sAw);
    gld_lds16(gA + (size_t)16 * K, sAw + 16 * 32);
    gld_lds16(gB, sBw);
    gld_lds16(gB + (size_t)16 * K, sBw + 16 * 32);
  }
  for (int kt = 0; kt < KT; ++kt) {
    __syncthreads();
    half8 af[4], bf[4];
#pragma unroll
    for (int i = 0; i < 4; ++i) af[i] = *(const half8*)(pA + i * 16 * 32);
#pragma unroll
    for (int j = 0; j < 4; ++j) bf[j] = *(const half8*)(pB + j * 16 * 32);
    __syncthreads();
    if (kt + 1 < KT) {
      const _Float16* ga = gA + (size_t)(kt + 1) * 32;
      const _Float16* gb = gB + (size_t)(kt + 1) * 32;
      gld_lds16(ga, sAw);
      gld_lds16(ga + (size_t)16 * K, sAw + 16 * 32);
      gld_lds16(gb, sBw);
      gld_lds16(gb + (size_t)16 * K, sBw + 16 * 32);
    }
#pragma unroll
    for (int i = 0; i < 4; ++i)
#pragma unroll
      for (int j = 0; j < 4; ++j)
        acc[i][j] =
            __builtin_amdgcn_mfma_f32_16x16x32_f16(af[i], bf[j], acc[i][j], 0, 0, 0);
  }
  const int lrow = wm * 64 + kb * 4;
  const int lcol = wn * 64 + fr;
#pragma unroll
  for (int i = 0; i < 4; ++i)
#pragma unroll
    for (int r = 0; r < 4; ++r)
#pragma unroll
      for (int j = 0; j < 4; ++j) {
        float v = acc[i][j][r] + b1f[lcol + j * 16];
        sy[lrow + i * 16 + r][lcol + j * 16] = (_Float16)(v > 0.f ? v : 0.f);
      }
  __syncthreads();
#pragma unroll
  for (int q = 0; q < 3; ++q) {
    const int idx = tid * 3 + q;
    const int n = idx / NCLS, c = idx % NCLS;
    if (row0 + n < N_NODES) {
      float s = b2f[c];
      const float* w2 = W2 + c * 128;
#pragma unroll 8
      for (int k = 0; k < 128; ++k) s += (float)sy[n][k] * w2[k];
      out[(size_t)(row0 + n) * NCLS + c] = s;
    }
  }
}

// ---------------------------------------------------------------------------
// Mega-cvt: all fp32->fp16 conversions in ONE launch.
// ---------------------------------------------------------------------------
__device__ __forceinline__ void cvt_pair(const float* __restrict__ in,
                                         _Float16* __restrict__ out, int i,
                                         int K, int Kp) {
  const int kp2 = Kp >> 1;
  const int r = i / kp2, c2 = (i % kp2) * 2;
  const float vx = (c2 < K) ? in[(size_t)r * K + c2] : 0.f;
  const float vy = (c2 + 1 < K) ? in[(size_t)r * K + c2 + 1] : 0.f;
  out[(size_t)r * Kp + c2] = (_Float16)vx;
  out[(size_t)r * Kp + c2 + 1] = (_Float16)vy;
}

#define CV_S0 (N_NODES * (K1PAD / 2))
#define CV_S1 (C1 * (K1PAD / 2))
#define CV_S2 (C1 * (C1 / 2))
#define CV_S3 (DH * (C1 / 2))
#define CV_S4 (128 * (DH / 2))
#define CV_TOT (CV_S0 + CV_S1 + CV_S2 + CV_S3 + CV_S4)

__global__ __launch_bounds__(256) void k_cvt_all(
    const float* __restrict__ x, const float* __restrict__ W1,
    const float* __restrict__ W2, const float* __restrict__ W3,
    const float* __restrict__ fcW, _Float16* __restrict__ xh,
    _Float16* __restrict__ w1h, _Float16* __restrict__ w2h,
    _Float16* __restrict__ w3h, _Float16* __restrict__ fwh) {
  int i = blockIdx.x * 256 + threadIdx.x;
  if (i < CV_S0) { cvt_pair(x, xh, i, F_INDIM, K1PAD); return; }
  i -= CV_S0;
  if (i < CV_S1) { cvt_pair(W1, w1h, i, F_INDIM, K1PAD); return; }
  i -= CV_S1;
  if (i < CV_S2) { cvt_pair(W2, w2h, i, C1, C1); return; }
  i -= CV_S2;
  if (i < CV_S3) { cvt_pair(W3, w3h, i, C1, C1); return; }
  i -= CV_S3;
  if (i < CV_S4) { cvt_pair(fcW, fwh, i, DH, DH); return; }
}

// ---------------------------------------------------------------------------
// Fold bias+BN for BOTH layers: A/B[0..1024) = layer1, [1024..2048) = layer2.
// ---------------------------------------------------------------------------
__global__ __launch_bounds__(256) void k_bnp2(
    const float* __restrict__ b1, const float* __restrict__ g1,
    const float* __restrict__ be1, const float* __restrict__ m1,
    const float* __restrict__ v1, const float* __restrict__ b2,
    const float* __restrict__ g2, const float* __restrict__ be2,
    const float* __restrict__ m2, const float* __restrict__ v2,
    float* __restrict__ A, float* __restrict__ B) {
  const int c = blockIdx.x * 256 + threadIdx.x;
  if (c >= 2 * C1) return;
  if (c < C1) {
    const float rs = rsqrtf(v1[c] + BN_EPS) * g1[c];
    A[c] = rs;
    B[c] = (b1[c] - m1[c]) * rs + be1[c];
  } else {
    const int d = c - C1;
    const float rs = rsqrtf(v2[d] + BN_EPS) * g2[d];
    A[c] = rs;
    B[c] = (b2[d] - m2[d]) * rs + be2[d];
  }
}

// ---------------------------------------------------------------------------
// alpha_s[n,h] = <h[n,h,:], a_src[h,:]> from fp16 h. Block = HH*64.
// ---------------------------------------------------------------------------
template <int HH>
__global__ __launch_bounds__(HH * 64) void k_alpha(
    const _Float16* __restrict__ h, const float* __restrict__ a_src,
    const float* __restrict__ a_dst, float* __restrict__ as_,
    float* __restrict__ ad_) {
  const int n = blockIdx.x;
  const int tid = threadIdx.x;
  const int head = tid >> 6;
  const int lane = tid & 63;
  const half4 hv = *(const half4*)(h + (size_t)n * HH * DH + head * DH + lane * 4);
  const float4 sv = *(reinterpret_cast<const float4*>(a_src + head * DH) + lane);
  const float4 dv = *(reinterpret_cast<const float4*>(a_dst + head * DH) + lane);
  const float h0 = (float)hv[0], h1 = (float)hv[1], h2 = (float)hv[2],
              h3 = (float)hv[3];
  float s1 = h0 * sv.x + h1 * sv.y + h2 * sv.z + h3 * sv.w;
  float s2 = h0 * dv.x + h1 * dv.y + h2 * dv.z + h3 * dv.w;
#pragma unroll
  for (int off = 32; off > 0; off >>= 1) {
    s1 += __shfl_down(s1, off);
    s2 += __shfl_down(s2, off);
  }
  if (lane == 0) {
    as_[n * HH + head] = s1;
    ad_[n * HH + head] = s2;
  }
}

// ---------------------------------------------------------------------------
// CSR build (cnt1 for count, cnt2 for fill -> both zeroed by one memset)
// ---------------------------------------------------------------------------
__global__ __launch_bounds__(256) void k_count(const int* __restrict__ ei,
                                               int* __restrict__ cnt) {
  const int e = blockIdx.x * 256 + threadIdx.x;
  if (e >= ETOT) return;
  const int t = (e < N_EDGES) ? ei[N_EDGES + e] : (e - N_EDGES);
  atomicAdd(&cnt[t], 1);
}

__global__ __launch_bounds__(256) void k_scan(const int* __restrict__ cnt,
                                              int* __restrict__ rowptr) {
  __shared__ int part[256];
  const int tid = threadIdx.x;
  const int chunk = (N_NODES + 255) / 256;  // 40
  const int b = tid * chunk;
  int sum = 0;
  for (int i = 0; i < chunk; i++) {
    const int idx = b + i;
    if (idx < N_NODES) sum += cnt[idx];
  }
  part[tid] = sum;
  __syncthreads();
  for (int off = 1; off < 256; off <<= 1) {
    int t2 = (tid >= off) ? part[tid - off] : 0;
    __syncthreads();
    part[tid] += t2;
    __syncthreads();
  }
  int run = part[tid] - sum;
  for (int i = 0; i < chunk; i++) {
    const int idx = b + i;
    if (idx < N_NODES) {
      rowptr[idx] = run;
      run += cnt[idx];
    }
  }
  if (tid == 255) rowptr[N_NODES] = part[255];
}

__global__ __launch_bounds__(256) void k_fill(
    const int* __restrict__ ei, const int* __restrict__ rowptr,
    int* __restrict__ fill, int* __restrict__ csr_src) {
  const int e = blockIdx.x * 256 + threadIdx.x;
  if (e >= ETOT) return;
  int s, t;
  if (e < N_EDGES) { s = ei[e]; t = ei[N_EDGES + e]; }
  else             { s = t = e - N_EDGES; }
  const int pos = rowptr[t] + atomicAdd(&fill[t], 1);
  csr_src[pos] = s;
}

// ---------------------------------------------------------------------------
// HH=4 aggregation, XCD-sliced, EDGE-FUSED (round 14): dst of every slot in
// row n IS n, so ad_[n,head] is block-uniform; w = exp(lrelu(as_[s,head]+adn))
// computed during staging. Softmax denom = in-register wsum (every lane sees
// every w). Removes k_edge (45us x3: 14x write-amplified scatter), ewc, den.
// ---------------------------------------------------------------------------
__global__ __launch_bounds__(64) void k_agg4s(
    const _Float16* __restrict__ h, const int* __restrict__ rowptr,
    const int* __restrict__ csr_src, const float* __restrict__ as_,
    const float* __restrict__ ad_, const float* __restrict__ Af,
    const float* __restrict__ Bf, _Float16* __restrict__ outh) {
  const int b = blockIdx.x;
  const int g = b & 7;            // column group -> XCD
  const int n = b >> 3;           // node
  const int lane = threadIdx.x;   // 0..63
  const int c0 = g * 128 + lane * 2;
  const int head = g >> 1;
  __shared__ int s_src[64];
  __shared__ float s_al[64];
  const float adn = ad_[n * 4 + head];
  float ax = 0.f, ay = 0.f, wsum = 0.f;
  const int beg = rowptr[n], end = rowptr[n + 1];
  for (int base = beg; base < end; base += 64) {
    const int cnt = min(64, end - base);
    __syncthreads();
    if (lane < cnt) {
      const int s = csr_src[base + lane];
      s_src[lane] = s;
      float e = as_[s * 4 + head] + adn;
      e = e > 0.f ? e : 0.2f * e;
      s_al[lane] = expf(e);
    }
    __syncthreads();
    int j = 0;
    const int nfull = cnt & ~7;
    for (; j < nfull; j += 8) {
      float w[8];
      half2v v[8];
#pragma unroll
      for (int u = 0; u < 8; ++u) {
        w[u] = s_al[j + u];
        v[u] = *(const half2v*)(h + (size_t)s_src[j + u] * C1 + c0);
      }
#pragma unroll
      for (int u = 0; u < 8; ++u) {
        ax += (float)v[u][0] * w[u];
        ay += (float)v[u][1] * w[u];
        wsum += w[u];
      }
    }
    for (; j < cnt; ++j) {
      const float w0 = s_al[j];
      const half2v v = *(const half2v*)(h + (size_t)s_src[j] * C1 + c0);
      ax += (float)v[0] * w0;
      ay += (float)v[1] * w0;
      wsum += w0;
    }
  }
  const float idn = 1.f / (wsum + 1e-16f);
  float r0 = ax * idn * Af[c0] + Bf[c0];
  float r1 = ay * idn * Af[c0 + 1] + Bf[c0 + 1];
  r0 = r0 > 0.f ? r0 : expm1f(r0);  // ELU
  r1 = r1 > 0.f ? r1 : expm1f(r1);
  half2v ov;
  ov[0] = (_Float16)r0;
  ov[1] = (_Float16)r1;
  *(half2v*)(outh + (size_t)n * C1 + c0) = ov;
}

// ---------------------------------------------------------------------------
// HH=1 aggregation (layer 3), edge-fused likewise. fp16 out (feeds fc12).
// ---------------------------------------------------------------------------
__global__ __launch_bounds__(64) void k_agg1(
    const _Float16* __restrict__ h, const int* __restrict__ rowptr,
    const int* __restrict__ csr_src, const float* __restrict__ as_,
    const float* __restrict__ ad_, const float* __restrict__ bias,
    _Float16* __restrict__ outh) {
  const int n = blockIdx.x;
  const int tid = threadIdx.x;
  const int c0 = tid * 4;
  __shared__ int s_src[64];
  __shared__ float s_al[64];
  const float adn = ad_[n];
  float acc[4] = {};
  float wsum = 0.f;
  const int beg = rowptr[n], end = rowptr[n + 1];
  for (int base = beg; base < end; base += 64) {
    const int cnt = min(64, end - base);
    __syncthreads();
    if (tid < cnt) {
      const int s = csr_src[base + tid];
      s_src[tid] = s;
      float e = as_[s] + adn;
      e = e > 0.f ? e : 0.2f * e;
      s_al[tid] = expf(e);
    }
    __syncthreads();
    int j = 0;
    const int nfull = cnt & ~7;
    for (; j < nfull; j += 8) {
      float w[8];
      half4 v[8];
#pragma unroll
      for (int u = 0; u < 8; ++u) {
        w[u] = s_al[j + u];
        v[u] = *(const half4*)(h + (size_t)s_src[j + u] * DH + c0);
      }
#pragma unroll
      for (int u = 0; u < 8; ++u) {
#pragma unroll
        for (int i = 0; i < 4; ++i) acc[i] += (float)v[u][i] * w[u];
        wsum += w[u];
      }
    }
    for (; j < cnt; ++j) {
      const float w0 = s_al[j];
      const half4 v = *(const half4*)(h + (size_t)s_src[j] * DH + c0);
#pragma unroll
      for (int i = 0; i < 4; ++i) acc[i] += (float)v[i] * w0;
      wsum += w0;
    }
  }
  const float idn = 1.f / (wsum + 1e-16f);
  half4 ov;
#pragma unroll
  for (int i = 0; i < 4; i++) {
    const int c = c0 + i;
    float val = acc[i] * idn + bias[c];
    val = val > 0.f ? val : expm1f(val);  // ELU
    ov[i] = (_Float16)val;
  }
  *(half4*)(outh + (size_t)n * DH + c0) = ov;
}

// ---------------------------------------------------------------------------
extern "C" void kernel_launch(void* const* d_in, const int* in_sizes, int n_in,
                              void* d_out, int out_size, void* d_ws,
                              size_t ws_size, hipStream_t stream) {
  const float* x    = (const float*)d_in[0];
  const int*   ei   = (const int*)d_in[1];
  const float* W1   = (const float*)d_in[2];
  const float* a1s  = (const float*)d_in[3];
  const float* a1d  = (const float*)d_in[4];
  const float* b1   = (const float*)d_in[5];
  const float* W2   = (const float*)d_in[6];
  const float* a2s  = (const float*)d_in[7];
  const float* a2d  = (const float*)d_in[8];
  const float* b2   = (const float*)d_in[9];
  const float* W3   = (const float*)d_in[10];
  const float* a3s  = (const float*)d_in[11];
  const float* a3d  = (const float*)d_in[12];
  const float* b3   = (const float*)d_in[13];
  const float* g1   = (const float*)d_in[14];
  const float* be1  = (const float*)d_in[15];
  const float* m1   = (const float*)d_in[16];
  const float* v1   = (const float*)d_in[17];
  const float* g2   = (const float*)d_in[18];
  const float* be2  = (const float*)d_in[19];
  const float* m2   = (const float*)d_in[20];
  const float* v2   = (const float*)d_in[21];
  const float* fc1W = (const float*)d_in[22];
  const float* fc1b = (const float*)d_in[23];
  const float* fc2W = (const float*)d_in[24];
  const float* fc2b = (const float*)d_in[25];
  float* out = (float*)d_out;

  char* p = (char*)d_ws;
  auto alloc = [&](size_t bytes) -> void* {
    void* r = (void*)p;
    p += (bytes + 255) & ~(size_t)255;
    return r;
  };
  _Float16* hA     = (_Float16*)alloc((size_t)M_PAD * C1 * 2);  // GEMM in (holds xh)
  _Float16* hG     = (_Float16*)alloc((size_t)M_PAD * C1 * 2);  // GEMM out
  _Float16* w1h    = (_Float16*)alloc((size_t)C1 * K1PAD * 2);
  _Float16* w2h    = (_Float16*)alloc((size_t)C1 * C1 * 2);
  _Float16* w3h    = (_Float16*)alloc((size_t)DH * C1 * 2);
  _Float16* fwh    = (_Float16*)alloc((size_t)128 * DH * 2);
  _Float16* y16    = (_Float16*)alloc((size_t)M_PAD * DH * 2);  // agg3 out
  float*    as_    = (float*)alloc((size_t)N_NODES * HEADS * 4);
  float*    ad_    = (float*)alloc((size_t)N_NODES * HEADS * 4);
  float*    Afold  = (float*)alloc((size_t)2 * C1 * 4);
  float*    Bfold  = (float*)alloc((size_t)2 * C1 * 4);
  int*      rowptr = (int*)alloc((size_t)(N_NODES + 1) * 4);
  int*      csrS   = (int*)alloc((size_t)ETOT * 4);
  // single zero-block: cnt1[N] cnt2[N]
  const size_t ZN = (size_t)N_NODES * 2 * 4;  // 80 KB
  char*     zbuf   = (char*)alloc(ZN);
  int*      cnt1   = (int*)zbuf;
  int*      cnt2   = cnt1 + N_NODES;

  const int eb = (ETOT + 255) / 256;
  _Float16* xh = hA;  // alias: [M_PAD][K1PAD], gemm1 reads before agg1 writes

  // ---- one memset for both CSR counters ----
  hipMemsetAsync(zbuf, 0, ZN, stream);
  // ---- CSR build ----
  k_count<<<eb, 256, 0, stream>>>(ei, cnt1);
  k_scan<<<1, 256, 0, stream>>>(cnt1, rowptr);
  k_fill<<<eb, 256, 0, stream>>>(ei, rowptr, cnt2, csrS);
  // ---- all conversions + BN folds (input-only deps) ----
  k_cvt_all<<<(CV_TOT + 255) / 256, 256, 0, stream>>>(
      x, W1, W2, W3, fc1W, xh, w1h, w2h, w3h, fwh);
  k_bnp2<<<(2 * C1 + 255) / 256, 256, 0, stream>>>(
      b1, g1, be1, m1, v1, b2, g2, be2, m2, v2, Afold, Bfold);

  // ---- Layer 1: GATConv(300 -> 4x256) + BN1 + ELU ----
  k_mfma_gemm<<<dim3(C1 / 128, M_PAD / 128), 256, 0, stream>>>(
      xh, w1h, hG, N_NODES, C1, K1PAD);
  k_alpha<4><<<N_NODES, 256, 0, stream>>>(hG, a1s, a1d, as_, ad_);
  k_agg4s<<<N_NODES * 8, 64, 0, stream>>>(hG, rowptr, csrS, as_, ad_,
                                          Afold, Bfold, hA);

  // ---- Layer 2: GATConv(1024 -> 4x256) + BN2 + ELU ----
  k_mfma_gemm<<<dim3(C1 / 128, M_PAD / 128), 256, 0, stream>>>(
      hA, w2h, hG, N_NODES, C1, C1);
  k_alpha<4><<<N_NODES, 256, 0, stream>>>(hG, a2s, a2d, as_, ad_);
  k_agg4s<<<N_NODES * 8, 64, 0, stream>>>(hG, rowptr, csrS, as_, ad_,
                                          Afold + C1, Bfold + C1, hA);

  // ---- Layer 3: GATConv(1024 -> 256, heads=1) + ELU ----
  k_mfma_gemm<<<dim3(DH / 128, M_PAD / 128), 256, 0, stream>>>(
      hA, w3h, hG, N_NODES, DH, C1);
  k_alpha<1><<<N_NODES, 64, 0, stream>>>(hG, a3s, a3d, as_, ad_);
  k_agg1<<<N_NODES, 64, 0, stream>>>(hG, rowptr, csrS, as_, ad_, b3, y16);

  // ---- Fused MLP head: fc1 MFMA + in-block fc2 ----
  k_fc12<<<M_PAD / 128, 256, 0, stream>>>(y16, fwh, fc1b, fc2W, fc2b, out);
}